// Round 1
// baseline (22475.406 us; speedup 1.0000x reference)
//
#include <hip/hip_runtime.h>
#include <math.h>

constexpr int H      = 1024;
constexpr int AA     = 8;
constexpr int T      = 64;
constexpr int NB     = 256;
constexpr int TWOH   = 2048;
constexpr int THREEH = 3072;
constexpr int KP     = 2056;   // 2H + A

constexpr long long OFF_Q  = (long long)T * NB * TWOH;   // 33554432
constexpr long long OFF_HX = 2LL * T * NB * TWOH;        // 67108864

__device__ __forceinline__ float sigf(float x) { return 1.0f / (1.0f + expf(-x)); }

// ---------------------------------------------------------------- init state
__global__ __launch_bounds__(256) void init_state_k(const float* __restrict__ hxs,
                                                    float* __restrict__ f0,
                                                    float* __restrict__ h0) {
    int i = blockIdx.x * 256 + threadIdx.x;   // 0 .. NB*H-1
    int n = i >> 10;
    int j = i & 1023;
    f0[i] = hxs[n * THREEH + j];
    h0[i] = hxs[n * THREEH + H + j];
}

// ---------------------------------------------------------------- p/q GEMMs
// z=0: p_dist = m*(h@pW[:, :H]^T + qmu@pW[:, H:2H]^T + a@pW[:, 2H:]^T) + p_b
// z=1: q_dist = m*(f@qW[:, :H]^T + c_t@qW[:, H:2H]^T + a@qW[:, 2H:]^T) + q_b
// 64x64 tile per block, 256 threads, 4x4 micro-tile, BK=16.
__global__ __launch_bounds__(256) void pq_gemm_k(
    int t,
    const float* __restrict__ fcur, const float* __restrict__ hcur,
    const float* __restrict__ hxs,  const float* __restrict__ c,
    const float* __restrict__ masks, const float* __restrict__ act,
    const float* __restrict__ pW, const float* __restrict__ pb,
    const float* __restrict__ qW, const float* __restrict__ qb,
    float* out)
{
    const int isQ = blockIdx.z;
    const int jb  = blockIdx.x;   // 0..31  (64 cols each)
    const int nb  = blockIdx.y;   // 0..3   (64 rows each)
    const int tid = threadIdx.x;
    const int tx  = tid & 15;
    const int ty  = tid >> 4;

    __shared__ float As[16][64];
    __shared__ float Bs[16][64];

    const float* __restrict__ W    = isQ ? qW : pW;
    const float* __restrict__ bias = isQ ? qb : pb;

    const int row0 = nb * 64;
    const int col0 = jb * 64;

    const int lr = tid >> 2;        // 0..63
    const int lk = (tid & 3) * 4;   // 0,4,8,12

    float acc[4][4] = {};

    for (int k0 = 0; k0 < TWOH; k0 += 16) {
        const int gk = k0 + lk;
        const int n  = row0 + lr;
        float4 xa;
        if (!isQ) {
            if (gk < H) {
                xa = *reinterpret_cast<const float4*>(&hcur[n * H + gk]);
            } else if (t == 0) {
                xa = *reinterpret_cast<const float4*>(&hxs[n * THREEH + TWOH + (gk - H)]);
            } else {
                xa = *reinterpret_cast<const float4*>(
                        &out[OFF_Q + ((long long)(t - 1) * NB + n) * TWOH + (gk - H)]);
            }
        } else {
            if (gk < H) {
                xa = *reinterpret_cast<const float4*>(&fcur[n * H + gk]);
            } else {
                xa = *reinterpret_cast<const float4*>(
                        &c[((long long)t * NB + n) * H + (gk - H)]);
            }
        }
        float4 wb = *reinterpret_cast<const float4*>(&W[(long long)(col0 + lr) * KP + gk]);

        __syncthreads();
        As[lk + 0][lr] = xa.x; As[lk + 1][lr] = xa.y;
        As[lk + 2][lr] = xa.z; As[lk + 3][lr] = xa.w;
        Bs[lk + 0][lr] = wb.x; Bs[lk + 1][lr] = wb.y;
        Bs[lk + 2][lr] = wb.z; Bs[lk + 3][lr] = wb.w;
        __syncthreads();

        #pragma unroll
        for (int k = 0; k < 16; k++) {
            float4 av = *reinterpret_cast<const float4*>(&As[k][ty * 4]);
            float4 bv = *reinterpret_cast<const float4*>(&Bs[k][tx * 4]);
            acc[0][0] += av.x * bv.x; acc[0][1] += av.x * bv.y;
            acc[0][2] += av.x * bv.z; acc[0][3] += av.x * bv.w;
            acc[1][0] += av.y * bv.x; acc[1][1] += av.y * bv.y;
            acc[1][2] += av.y * bv.z; acc[1][3] += av.y * bv.w;
            acc[2][0] += av.z * bv.x; acc[2][1] += av.z * bv.y;
            acc[2][2] += av.z * bv.z; acc[2][3] += av.z * bv.w;
            acc[3][0] += av.w * bv.x; acc[3][1] += av.w * bv.y;
            acc[3][2] += av.w * bv.z; acc[3][3] += av.w * bv.w;
        }
    }

    // action part (K = 8) + bias + mask + store
    float wa[4][8];
    float bb[4];
    #pragma unroll
    for (int j = 0; j < 4; j++) {
        const int col = col0 + tx * 4 + j;
        const float* wr = &W[(long long)col * KP + TWOH];
        #pragma unroll
        for (int u = 0; u < 8; u++) wa[j][u] = wr[u];
        bb[j] = bias[col];
    }
    const long long obase = isQ ? OFF_Q : 0LL;
    #pragma unroll
    for (int i = 0; i < 4; i++) {
        const int n = row0 + ty * 4 + i;
        const float m = masks[t * NB + n];
        const float4 a0 = *reinterpret_cast<const float4*>(&act[((long long)t * NB + n) * AA]);
        const float4 a1 = *reinterpret_cast<const float4*>(&act[((long long)t * NB + n) * AA + 4]);
        float res[4];
        #pragma unroll
        for (int j = 0; j < 4; j++) {
            float s = acc[i][j];
            s += a0.x * wa[j][0] + a0.y * wa[j][1] + a0.z * wa[j][2] + a0.w * wa[j][3];
            s += a1.x * wa[j][4] + a1.y * wa[j][5] + a1.z * wa[j][6] + a1.w * wa[j][7];
            res[j] = m * s + bb[j];
        }
        *reinterpret_cast<float4*>(
            &out[obase + ((long long)t * NB + n) * TWOH + col0 + tx * 4]) =
            make_float4(res[0], res[1], res[2], res[3]);
    }
}

// ---------------------------------------------------------------- f/h GRU cells
// z=0: f_new = GRU(x=c_t,            h=f*m, fW*)
// z=1: h_new = GRU(x=p_mu=acc_p[:H], h=h*m, hW*)
// Block: 32 rows x 64 cols, 256 threads, per thread 2x4 outputs x 6 accumulators.
__global__ __launch_bounds__(256) void fh_gru_k(
    int t,
    const float* __restrict__ fcur, const float* __restrict__ hcur,
    float* __restrict__ fnxt, float* __restrict__ hnxt,
    const float* __restrict__ c, const float* __restrict__ masks,
    const float* __restrict__ fWih, const float* __restrict__ fWhh,
    const float* __restrict__ fbih, const float* __restrict__ fbhh,
    const float* __restrict__ hWih, const float* __restrict__ hWhh,
    const float* __restrict__ hbih, const float* __restrict__ hbhh,
    const float* __restrict__ outp)
{
    const int zz = blockIdx.z;
    const int jb = blockIdx.x;   // 0..15 (64 cols each)
    const int nb = blockIdx.y;   // 0..7  (32 rows each)
    const int tid = threadIdx.x;
    const int tx = tid & 15, ty = tid >> 4;

    __shared__ float Xs[16][32];
    __shared__ float Hs[16][32];
    __shared__ float Wis[3][16][64];
    __shared__ float Whs[3][16][64];

    const float* Wih  = zz ? hWih : fWih;
    const float* Whh  = zz ? hWhh : fWhh;
    const float* bih  = zz ? hbih : fbih;
    const float* bhh  = zz ? hbhh : fbhh;
    const float* hprev = zz ? hcur : fcur;
    float* dst = zz ? hnxt : fnxt;

    const int row0 = nb * 32;
    const int col0 = jb * 64;

    float ai[3][2][4] = {};
    float ah[3][2][4] = {};

    const int xh = tid >> 7;          // 0: X tile, 1: H tile
    const int lr = (tid >> 2) & 31;   // row 0..31
    const int lu = tid & 3;           // k-quad

    for (int k0 = 0; k0 < H; k0 += 16) {
        // global loads into registers
        float4 v;
        {
            const int n = row0 + lr;
            if (xh == 0) {
                if (zz == 0)
                    v = *reinterpret_cast<const float4*>(&c[((long long)t * NB + n) * H + k0 + lu * 4]);
                else
                    v = *reinterpret_cast<const float4*>(&outp[((long long)t * NB + n) * TWOH + k0 + lu * 4]);
            } else {
                v = *reinterpret_cast<const float4*>(&hprev[n * H + k0 + lu * 4]);
                const float m = masks[t * NB + n];
                v.x *= m; v.y *= m; v.z *= m; v.w *= m;
            }
        }
        float4 wv[6];
        #pragma unroll
        for (int p = 0; p < 6; p++) {
            const int L  = tid + p * 256;   // 0..1535
            const int tt = L >> 8;          // 0..5
            const int r  = (L >> 2) & 63;   // col within tile
            const int u  = L & 3;
            const int g  = tt % 3;
            const float* Wp = (tt < 3) ? Wih : Whh;
            wv[p] = *reinterpret_cast<const float4*>(&Wp[(long long)(g * H + col0 + r) * H + k0 + u * 4]);
        }

        __syncthreads();
        {
            float* Ts = (xh == 0) ? &Xs[0][0] : &Hs[0][0];
            Ts[(lu * 4 + 0) * 32 + lr] = v.x;
            Ts[(lu * 4 + 1) * 32 + lr] = v.y;
            Ts[(lu * 4 + 2) * 32 + lr] = v.z;
            Ts[(lu * 4 + 3) * 32 + lr] = v.w;
        }
        #pragma unroll
        for (int p = 0; p < 6; p++) {
            const int L  = tid + p * 256;
            const int tt = L >> 8;
            const int r  = (L >> 2) & 63;
            const int u  = L & 3;
            const int g  = tt % 3;
            float* Ts = (tt < 3) ? &Wis[g][0][0] : &Whs[g][0][0];
            Ts[(u * 4 + 0) * 64 + r] = wv[p].x;
            Ts[(u * 4 + 1) * 64 + r] = wv[p].y;
            Ts[(u * 4 + 2) * 64 + r] = wv[p].z;
            Ts[(u * 4 + 3) * 64 + r] = wv[p].w;
        }
        __syncthreads();

        #pragma unroll
        for (int k = 0; k < 16; k++) {
            const float x0 = Xs[k][ty * 2 + 0];
            const float x1 = Xs[k][ty * 2 + 1];
            const float h0 = Hs[k][ty * 2 + 0];
            const float h1 = Hs[k][ty * 2 + 1];
            #pragma unroll
            for (int g = 0; g < 3; g++) {
                float4 wi = *reinterpret_cast<const float4*>(&Wis[g][k][tx * 4]);
                float4 wh = *reinterpret_cast<const float4*>(&Whs[g][k][tx * 4]);
                ai[g][0][0] += x0 * wi.x; ai[g][0][1] += x0 * wi.y;
                ai[g][0][2] += x0 * wi.z; ai[g][0][3] += x0 * wi.w;
                ai[g][1][0] += x1 * wi.x; ai[g][1][1] += x1 * wi.y;
                ai[g][1][2] += x1 * wi.z; ai[g][1][3] += x1 * wi.w;
                ah[g][0][0] += h0 * wh.x; ah[g][0][1] += h0 * wh.y;
                ah[g][0][2] += h0 * wh.z; ah[g][0][3] += h0 * wh.w;
                ah[g][1][0] += h1 * wh.x; ah[g][1][1] += h1 * wh.y;
                ah[g][1][2] += h1 * wh.z; ah[g][1][3] += h1 * wh.w;
            }
        }
    }

    #pragma unroll
    for (int i = 0; i < 2; i++) {
        const int n = row0 + ty * 2 + i;
        const float m = masks[t * NB + n];
        #pragma unroll
        for (int j = 0; j < 4; j++) {
            const int col = col0 + tx * 4 + j;
            const float hm = hprev[n * H + col] * m;
            const float r  = sigf(ai[0][i][j] + bih[col]         + ah[0][i][j] + bhh[col]);
            const float z  = sigf(ai[1][i][j] + bih[col + H]     + ah[1][i][j] + bhh[col + H]);
            const float nn = tanhf(ai[2][i][j] + bih[col + 2*H] + r * (ah[2][i][j] + bhh[col + 2*H]));
            dst[n * H + col] = (1.0f - z) * nn + z * hm;
        }
    }
}

// ---------------------------------------------------------------- final hxs_out
__global__ __launch_bounds__(256) void write_hxs_k(const float* __restrict__ fS,
                                                   const float* __restrict__ hS,
                                                   float* out) {
    int i = blockIdx.x * 256 + threadIdx.x;   // 0 .. NB*THREEH-1
    int n = i / THREEH;
    int j = i - n * THREEH;
    float v;
    if (j < H)          v = fS[n * H + j];
    else if (j < TWOH)  v = hS[n * H + (j - H)];
    else                v = out[OFF_Q + ((long long)(T - 1) * NB + n) * TWOH + (j - TWOH)];
    out[OFF_HX + i] = v;
}

// ---------------------------------------------------------------- launcher
extern "C" void kernel_launch(void* const* d_in, const int* in_sizes, int n_in,
                              void* d_out, int out_size, void* d_ws, size_t ws_size,
                              hipStream_t stream) {
    (void)in_sizes; (void)n_in; (void)out_size; (void)ws_size;

    const float* c     = (const float*)d_in[0];
    const float* hxs   = (const float*)d_in[1];
    const float* masks = (const float*)d_in[2];
    const float* act   = (const float*)d_in[3];
    const float* hWih  = (const float*)d_in[4];
    const float* hWhh  = (const float*)d_in[5];
    const float* hbih  = (const float*)d_in[6];
    const float* hbhh  = (const float*)d_in[7];
    const float* fWih  = (const float*)d_in[8];
    const float* fWhh  = (const float*)d_in[9];
    const float* fbih  = (const float*)d_in[10];
    const float* fbhh  = (const float*)d_in[11];
    const float* pW    = (const float*)d_in[12];
    const float* pb    = (const float*)d_in[13];
    const float* qW    = (const float*)d_in[14];
    const float* qb    = (const float*)d_in[15];

    float* out = (float*)d_out;
    float* ws  = (float*)d_ws;

    float* fbuf[2] = { ws,              ws + (size_t)NB * H };
    float* hbuf[2] = { ws + 2ULL*NB*H,  ws + 3ULL*NB*H };

    init_state_k<<<dim3((NB * H) / 256), dim3(256), 0, stream>>>(hxs, fbuf[0], hbuf[0]);

    for (int t = 0; t < T; t++) {
        const int cur = t & 1, nxt = cur ^ 1;
        pq_gemm_k<<<dim3(32, 4, 2), dim3(256), 0, stream>>>(
            t, fbuf[cur], hbuf[cur], hxs, c, masks, act, pW, pb, qW, qb, out);
        fh_gru_k<<<dim3(16, 8, 2), dim3(256), 0, stream>>>(
            t, fbuf[cur], hbuf[cur], fbuf[nxt], hbuf[nxt], c, masks,
            fWih, fWhh, fbih, fbhh, hWih, hWhh, hbih, hbhh, out);
    }

    write_hxs_k<<<dim3((NB * THREEH) / 256), dim3(256), 0, stream>>>(fbuf[0], hbuf[0], out);
}

// Round 2
// 9044.454 us; speedup vs baseline: 2.4850x; 2.4850x over previous
//
#include <hip/hip_runtime.h>
#include <math.h>

typedef __attribute__((ext_vector_type(8))) __bf16 bf16x8;
typedef __attribute__((ext_vector_type(4))) float f32x4;

constexpr int H      = 1024;
constexpr int T      = 64;
constexpr int NB     = 256;
constexpr int TWOH   = 2048;
constexpr int THREEH = 3072;

constexpr long long OFF_Q  = 33554432LL;   // T*NB*2H
constexpr long long OFF_HX = 67108864LL;   // 2*T*NB*2H

// bf16 weight buffer sub-offsets (elements), order: pWh,pWq,qWf,qWc,fWih,fWhh,hWih,hWhh
constexpr long long W_PWH  = 0;
constexpr long long W_PWQ  = 2097152;
constexpr long long W_QWF  = 4194304;
constexpr long long W_QWC  = 6291456;
constexpr long long W_FWIH = 8388608;
constexpr long long W_FWHH = 11534336;
constexpr long long W_HWIH = 14680064;
constexpr long long W_HWHH = 17825792;
constexpr long long W_TOT  = 20971520;     // elements (41,943,040 bytes)

#define LD4(p) (*reinterpret_cast<const float4*>(p))

__device__ __forceinline__ float sigf(float x) { return 1.0f / (1.0f + expf(-x)); }

__device__ __forceinline__ void gload_lds16(const void* g, void* l) {
    __builtin_amdgcn_global_load_lds(
        (const __attribute__((address_space(1))) uint32_t*)g,
        (__attribute__((address_space(3))) uint32_t*)l,
        16, 0, 0);
}

// ---------------------------------------------------------------- weight convert
__global__ __launch_bounds__(256) void wcvt_k(
    const float* __restrict__ pW, const float* __restrict__ qW,
    const float* __restrict__ fWih, const float* __restrict__ fWhh,
    const float* __restrict__ hWih, const float* __restrict__ hWhh,
    __bf16* __restrict__ Wbf)
{
    long i = (long)blockIdx.x * 256 + threadIdx.x;   // one thread = 8 elems
    int row = (int)(i >> 7);
    int kq  = ((int)i & 127) * 8;
    const float* src; int stride; int koff = 0; int r;
    if (row < 2048)       { src = pW;   stride = 2056; koff = 0;    r = row; }
    else if (row < 4096)  { src = pW;   stride = 2056; koff = 1024; r = row - 2048; }
    else if (row < 6144)  { src = qW;   stride = 2056; koff = 0;    r = row - 4096; }
    else if (row < 8192)  { src = qW;   stride = 2056; koff = 1024; r = row - 6144; }
    else if (row < 11264) { src = fWih; stride = 1024; r = row - 8192; }
    else if (row < 14336) { src = fWhh; stride = 1024; r = row - 11264; }
    else if (row < 17408) { src = hWih; stride = 1024; r = row - 14336; }
    else                  { src = hWhh; stride = 1024; r = row - 17408; }
    const float* p = src + (long)r * stride + koff + kq;
    float4 a = LD4(p), b = LD4(p + 4);
    bf16x8 v;
    v[0] = (__bf16)a.x; v[1] = (__bf16)a.y; v[2] = (__bf16)a.z; v[3] = (__bf16)a.w;
    v[4] = (__bf16)b.x; v[5] = (__bf16)b.y; v[6] = (__bf16)b.z; v[7] = (__bf16)b.w;
    *reinterpret_cast<bf16x8*>(Wbf + (long)row * 1024 + kq) = v;
}

// ---------------------------------------------------------------- init / final
__global__ __launch_bounds__(256) void init_state_k(const float* __restrict__ hxs,
                                                    float* __restrict__ f0,
                                                    float* __restrict__ h0) {
    int i = blockIdx.x * 256 + threadIdx.x;
    int n = i >> 10, j = i & 1023;
    f0[i] = hxs[n * THREEH + j];
    h0[i] = hxs[n * THREEH + H + j];
}

__global__ __launch_bounds__(256) void write_hxs_k(const float* __restrict__ fS,
                                                   const float* __restrict__ hS,
                                                   float* out) {
    int i = blockIdx.x * 256 + threadIdx.x;
    int n = i / THREEH;
    int j = i - n * THREEH;
    float v;
    if (j < H)          v = fS[n * H + j];
    else if (j < TWOH)  v = hS[n * H + (j - H)];
    else                v = out[OFF_Q + ((long)(T - 1) * NB + n) * TWOH + (j - TWOH)];
    out[OFF_HX + i] = v;
}

// ---------------------------------------------------------------- MFMA 2-seg GEMM core
// Block: 256 thr = 4 waves (2x2), tile 128x64, BK=64, K=1024 per segment.
// seg0 -> accA, seg1 -> accB. LDS XOR-swizzled (slot ^= row&7) both sides.
struct GemmArgs {
    const float* A0; long long lda0; int msk0;
    const float* A1; long long lda1; int msk1;
    const __bf16* B0; const __bf16* B1;
};

__device__ __forceinline__ void gemm_block(
    int tid, int row0, const GemmArgs& ga, const float* __restrict__ mrow,
    __bf16* Alds, __bf16* Blds, f32x4 (&accA)[4][2], f32x4 (&accB)[4][2])
{
    const int r    = tid >> 1;
    const int hf   = tid & 1;
    const int wuni = tid >> 6;
    const int lane = tid & 63;
    const int l15  = lane & 15, lg = lane >> 4;
    const int wr   = wuni >> 1, wc = wuni & 1;
    char* Ab = (char*)Alds;
    char* Bb = (char*)Blds;

    auto seg = [&](const float* __restrict__ A, long long lda, int msk,
                   const __bf16* __restrict__ Bw, f32x4 (&acc)[4][2]) {
        const float mm = msk ? mrow[row0 + r] : 1.0f;
        const float* ap = A + (long long)(row0 + r) * lda + hf * 32;
        float4 pre[8];
        #pragma unroll
        for (int j = 0; j < 8; ++j) pre[j] = LD4(ap + j * 4);

        for (int kb = 0; kb < 16; ++kb) {
            // B tile: global_load_lds, pre-swizzled source
            #pragma unroll
            for (int ch = 0; ch < 2; ++ch) {
                const int Lb = wuni * 1024 + ch * 4096;     // wave-uniform LDS base
                const int L  = Lb + lane * 16;
                const int colr = L >> 7;
                const int s8   = (L >> 4) & 7;
                gload_lds16(Bw + (long long)colr * 1024 + kb * 64 + ((s8 ^ (colr & 7)) * 8),
                            Bb + Lb);
            }
            // A tile: cvt fp32->bf16 (+mask), swizzled ds_write_b128
            #pragma unroll
            for (int q = 0; q < 4; ++q) {
                float4 u = pre[2 * q], v2 = pre[2 * q + 1];
                bf16x8 w;
                w[0] = (__bf16)(u.x * mm);  w[1] = (__bf16)(u.y * mm);
                w[2] = (__bf16)(u.z * mm);  w[3] = (__bf16)(u.w * mm);
                w[4] = (__bf16)(v2.x * mm); w[5] = (__bf16)(v2.y * mm);
                w[6] = (__bf16)(v2.z * mm); w[7] = (__bf16)(v2.w * mm);
                const int s8 = hf * 4 + q;
                *reinterpret_cast<bf16x8*>(Ab + r * 128 + ((s8 ^ (r & 7)) << 4)) = w;
            }
            __syncthreads();
            // prefetch next A tile into regs (overlaps frag-reads+MFMA)
            if (kb < 15) {
                const float* apn = ap + (kb + 1) * 64;
                #pragma unroll
                for (int j = 0; j < 8; ++j) pre[j] = LD4(apn + j * 4);
            }
            bf16x8 af[4][2], bfv[2][2];
            #pragma unroll
            for (int fr = 0; fr < 4; ++fr) {
                const int rr = wr * 64 + fr * 16 + l15;
                #pragma unroll
                for (int kk = 0; kk < 2; ++kk)
                    af[fr][kk] = *reinterpret_cast<bf16x8*>(
                        Ab + rr * 128 + (((kk * 4 + lg) ^ (rr & 7)) << 4));
            }
            #pragma unroll
            for (int fc = 0; fc < 2; ++fc) {
                const int cr = wc * 32 + fc * 16 + l15;
                #pragma unroll
                for (int kk = 0; kk < 2; ++kk)
                    bfv[fc][kk] = *reinterpret_cast<bf16x8*>(
                        Bb + cr * 128 + (((kk * 4 + lg) ^ (cr & 7)) << 4));
            }
            #pragma unroll
            for (int kk = 0; kk < 2; ++kk)
                #pragma unroll
                for (int fr = 0; fr < 4; ++fr)
                    #pragma unroll
                    for (int fc = 0; fc < 2; ++fc)
                        acc[fr][fc] = __builtin_amdgcn_mfma_f32_16x16x32_bf16(
                            af[fr][kk], bfv[fc][kk], acc[fr][fc], 0, 0, 0);
            __syncthreads();
        }
    };
    seg(ga.A0, ga.lda0, ga.msk0, ga.B0, accA);
    seg(ga.A1, ga.lda1, ga.msk1, ga.B1, accB);
}

// ---------------------------------------------------------------- GRU combine
__device__ __forceinline__ float gru1(float Sr, float Sz, float Sn, float Hnv,
                                      float bri, float brh, float bzi, float bzh,
                                      float bni, float bnh, float hm) {
    float rg = sigf(Sr + bri + brh);
    float zg = sigf(Sz + bzi + bzh);
    float ng = tanhf(Sn - Hnv + bni + rg * (Hnv + bnh));
    return (1.f - zg) * ng + zg * hm;
}

__device__ __forceinline__ void comb_body(
    int bx, int tid, const float* __restrict__ S, const float* __restrict__ Hn,
    const float* __restrict__ bih, const float* __restrict__ bhh,
    const float* __restrict__ hprev, const float* __restrict__ mrow,
    float* __restrict__ dst)
{
    #pragma unroll 4
    for (int u = 0; u < 16; ++u) {
        const int e4 = bx * 4096 + u * 256 + tid;   // 0..65535
        const int n = e4 >> 8;
        const int k = (e4 & 255) * 4;
        float4 sr = LD4(S + (long long)n * THREEH + k);
        float4 sz = LD4(S + (long long)n * THREEH + H + k);
        float4 sn = LD4(S + (long long)n * THREEH + TWOH + k);
        float4 hn = LD4(Hn + (long long)n * H + k);
        float4 b0i = LD4(bih + k),        b0h = LD4(bhh + k);
        float4 b1i = LD4(bih + H + k),    b1h = LD4(bhh + H + k);
        float4 b2i = LD4(bih + TWOH + k), b2h = LD4(bhh + TWOH + k);
        float4 hp = LD4(hprev + (long long)n * H + k);
        const float m = mrow[n];
        float4 o;
        o.x = gru1(sr.x, sz.x, sn.x, hn.x, b0i.x, b0h.x, b1i.x, b1h.x, b2i.x, b2h.x, hp.x * m);
        o.y = gru1(sr.y, sz.y, sn.y, hn.y, b0i.y, b0h.y, b1i.y, b1h.y, b2i.y, b2h.y, hp.y * m);
        o.z = gru1(sr.z, sz.z, sn.z, hn.z, b0i.z, b0h.z, b1i.z, b1h.z, b2i.z, b2h.z, hp.z * m);
        o.w = gru1(sr.w, sz.w, sn.w, hn.w, b0i.w, b0h.w, b1i.w, b1h.w, b2i.w, b2h.w, hp.w * m);
        *reinterpret_cast<float4*>(dst + (long long)n * H + k) = o;
    }
}

// ---------------------------------------------------------------- step kernels
// step1: blocks [0,64) P, [64,128) Q, [128,224) F-gates
__global__ __launch_bounds__(256) void step1_k(
    int t,
    const float* __restrict__ fcur, const float* __restrict__ hcur,
    const float* __restrict__ qmuP, long long qmuS,
    const float* __restrict__ c, const float* __restrict__ masks,
    const float* __restrict__ act,
    const float* __restrict__ pW, const float* __restrict__ pb,
    const float* __restrict__ qW, const float* __restrict__ qb,
    const __bf16* __restrict__ Wbf,
    float* __restrict__ Sf, float* __restrict__ Hnf,
    float* __restrict__ out)
{
    __shared__ __bf16 Alds[128 * 64];
    __shared__ __bf16 Blds[64 * 64];
    const int tid = threadIdx.x;
    int b = blockIdx.x;
    int btype, rb, cb;
    if (b < 64)       { btype = 0; rb = b >> 5; cb = b & 31; }
    else if (b < 128) { btype = 1; b -= 64; rb = b >> 5; cb = b & 31; }
    else              { btype = 2; b -= 128; rb = b / 48; cb = b % 48; }
    const int row0 = rb * 128, col0 = cb * 64;
    const float* mrow = masks + (long long)t * NB;
    const float* ct   = c + (long long)t * NB * H;

    GemmArgs ga;
    if (btype == 0)
        ga = { hcur, 1024, 0, qmuP, qmuS, 0,
               Wbf + W_PWH + (long long)col0 * 1024, Wbf + W_PWQ + (long long)col0 * 1024 };
    else if (btype == 1)
        ga = { fcur, 1024, 0, ct, 1024, 0,
               Wbf + W_QWF + (long long)col0 * 1024, Wbf + W_QWC + (long long)col0 * 1024 };
    else
        ga = { ct, 1024, 0, fcur, 1024, 1,
               Wbf + W_FWIH + (long long)col0 * 1024, Wbf + W_FWHH + (long long)col0 * 1024 };

    f32x4 accA[4][2] = {}; f32x4 accB[4][2] = {};
    gemm_block(tid, row0, ga, mrow, Alds, Blds, accA, accB);

    const int wuni = tid >> 6, lane = tid & 63, l15 = lane & 15, lg = lane >> 4;
    const int wr = wuni >> 1, wc = wuni & 1;

    if (btype <= 1) {
        const float* Wfull = btype ? qW : pW;
        const float* bias  = btype ? qb : pb;
        float* ob = out + (btype ? OFF_Q : 0) + (long long)t * NB * TWOH;
        float wa[2][8]; float bb2[2]; int gcs[2];
        #pragma unroll
        for (int fc = 0; fc < 2; ++fc) {
            const int gc = col0 + wc * 32 + fc * 16 + l15; gcs[fc] = gc;
            const float* wp = Wfull + (long long)gc * 2056 + 2048;
            float4 x0 = LD4(wp), x1 = LD4(wp + 4);
            wa[fc][0] = x0.x; wa[fc][1] = x0.y; wa[fc][2] = x0.z; wa[fc][3] = x0.w;
            wa[fc][4] = x1.x; wa[fc][5] = x1.y; wa[fc][6] = x1.z; wa[fc][7] = x1.w;
            bb2[fc] = bias[gc];
        }
        #pragma unroll
        for (int fr = 0; fr < 4; ++fr)
            #pragma unroll
            for (int j = 0; j < 4; ++j) {
                const int n = row0 + wr * 64 + fr * 16 + lg * 4 + j;
                const float m = mrow[n];
                const float* ar = act + ((long long)t * NB + n) * 8;
                float4 a0 = LD4(ar), a1 = LD4(ar + 4);
                #pragma unroll
                for (int fc = 0; fc < 2; ++fc) {
                    float dot = a0.x * wa[fc][0] + a0.y * wa[fc][1] + a0.z * wa[fc][2] + a0.w * wa[fc][3]
                              + a1.x * wa[fc][4] + a1.y * wa[fc][5] + a1.z * wa[fc][6] + a1.w * wa[fc][7];
                    float s = accA[fr][fc][j] + accB[fr][fc][j] + dot;
                    ob[(long long)n * TWOH + gcs[fc]] = m * s + bb2[fc];
                }
            }
    } else {
        #pragma unroll
        for (int fr = 0; fr < 4; ++fr)
            #pragma unroll
            for (int j = 0; j < 4; ++j) {
                const int n = row0 + wr * 64 + fr * 16 + lg * 4 + j;
                #pragma unroll
                for (int fc = 0; fc < 2; ++fc) {
                    const int gc = col0 + wc * 32 + fc * 16 + l15;
                    Sf[(long long)n * THREEH + gc] = accA[fr][fc][j] + accB[fr][fc][j];
                    if (col0 >= TWOH) Hnf[(long long)n * H + gc - TWOH] = accB[fr][fc][j];
                }
            }
    }
}

// step2: blocks [0,96) H-gates, [96,112) f-combine
__global__ __launch_bounds__(256) void step2_k(
    int t,
    const float* __restrict__ hcur, const float* __restrict__ masks,
    const __bf16* __restrict__ Wbf,
    const float* __restrict__ out,
    float* __restrict__ Sh, float* __restrict__ Hnh,
    const float* __restrict__ Sf, const float* __restrict__ Hnf,
    const float* __restrict__ fbih, const float* __restrict__ fbhh,
    const float* __restrict__ fcur, float* __restrict__ fnxt)
{
    __shared__ __bf16 Alds[128 * 64];
    __shared__ __bf16 Blds[64 * 64];
    const int tid = threadIdx.x;
    const float* mrow = masks + (long long)t * NB;
    if (blockIdx.x < 96) {
        int b = blockIdx.x;
        const int rb = b / 48, cb = b % 48;
        const int row0 = rb * 128, col0 = cb * 64;
        const float* pmu = out + (long long)t * NB * TWOH;   // p_mu cols < 1024, stride 2048
        GemmArgs ga = { pmu, TWOH, 0, hcur, 1024, 1,
                        Wbf + W_HWIH + (long long)col0 * 1024, Wbf + W_HWHH + (long long)col0 * 1024 };
        f32x4 accA[4][2] = {}; f32x4 accB[4][2] = {};
        gemm_block(tid, row0, ga, mrow, Alds, Blds, accA, accB);
        const int wuni = tid >> 6, lane = tid & 63, l15 = lane & 15, lg = lane >> 4;
        const int wr = wuni >> 1, wc = wuni & 1;
        #pragma unroll
        for (int fr = 0; fr < 4; ++fr)
            #pragma unroll
            for (int j = 0; j < 4; ++j) {
                const int n = row0 + wr * 64 + fr * 16 + lg * 4 + j;
                #pragma unroll
                for (int fc = 0; fc < 2; ++fc) {
                    const int gc = col0 + wc * 32 + fc * 16 + l15;
                    Sh[(long long)n * THREEH + gc] = accA[fr][fc][j] + accB[fr][fc][j];
                    if (col0 >= TWOH) Hnh[(long long)n * H + gc - TWOH] = accB[fr][fc][j];
                }
            }
    } else {
        comb_body(blockIdx.x - 96, tid, Sf, Hnf, fbih, fbhh, fcur, mrow, fnxt);
    }
}

// step3: h-combine
__global__ __launch_bounds__(256) void step3_k(
    int t,
    const float* __restrict__ Sh, const float* __restrict__ Hnh,
    const float* __restrict__ hbih, const float* __restrict__ hbhh,
    const float* __restrict__ hcur, const float* __restrict__ masks,
    float* __restrict__ hnxt)
{
    comb_body(blockIdx.x, threadIdx.x, Sh, Hnh, hbih, hbhh, hcur,
              masks + (long long)t * NB, hnxt);
}

// ---------------------------------------------------------------- launcher
extern "C" void kernel_launch(void* const* d_in, const int* in_sizes, int n_in,
                              void* d_out, int out_size, void* d_ws, size_t ws_size,
                              hipStream_t stream) {
    (void)in_sizes; (void)n_in; (void)out_size; (void)ws_size;

    const float* c     = (const float*)d_in[0];
    const float* hxs   = (const float*)d_in[1];
    const float* masks = (const float*)d_in[2];
    const float* act   = (const float*)d_in[3];
    const float* hWih  = (const float*)d_in[4];
    const float* hWhh  = (const float*)d_in[5];
    const float* hbih  = (const float*)d_in[6];
    const float* hbhh  = (const float*)d_in[7];
    const float* fWih  = (const float*)d_in[8];
    const float* fWhh  = (const float*)d_in[9];
    const float* fbih  = (const float*)d_in[10];
    const float* fbhh  = (const float*)d_in[11];
    const float* pW    = (const float*)d_in[12];
    const float* pb    = (const float*)d_in[13];
    const float* qW    = (const float*)d_in[14];
    const float* qb    = (const float*)d_in[15];

    float* out = (float*)d_out;
    char*  wsb = (char*)d_ws;

    __bf16* Wbf = (__bf16*)wsb;                                  // 41,943,040 B
    float* fst[2] = { (float*)(wsb + 41943040LL),
                      (float*)(wsb + 41943040LL + 1048576LL) };
    float* hst[2] = { (float*)(wsb + 41943040LL + 2097152LL),
                      (float*)(wsb + 41943040LL + 3145728LL) };
    float* Sf  = (float*)(wsb + 41943040LL + 4194304LL);         // 256x3072 f32
    float* Hnf = Sf + (long long)NB * THREEH;                    // 256x1024
    float* Sh  = Hnf + (long long)NB * H;
    float* Hnh = Sh + (long long)NB * THREEH;
    // total ws use: ~54.5 MB

    wcvt_k<<<dim3(10240), dim3(256), 0, stream>>>(pW, qW, fWih, fWhh, hWih, hWhh, Wbf);
    init_state_k<<<dim3(1024), dim3(256), 0, stream>>>(hxs, fst[0], hst[0]);

    for (int t = 0; t < T; ++t) {
        const int cur = t & 1, nxt = cur ^ 1;
        const float* qmuP; long long qmuS;
        if (t == 0) { qmuP = hxs + TWOH; qmuS = THREEH; }
        else        { qmuP = out + OFF_Q + (long long)(t - 1) * NB * TWOH; qmuS = TWOH; }

        step1_k<<<dim3(224), dim3(256), 0, stream>>>(
            t, fst[cur], hst[cur], qmuP, qmuS, c, masks, act,
            pW, pb, qW, qb, Wbf, Sf, Hnf, out);
        step2_k<<<dim3(112), dim3(256), 0, stream>>>(
            t, hst[cur], masks, Wbf, out, Sh, Hnh, Sf, Hnf, fbih, fbhh,
            fst[cur], fst[nxt]);
        step3_k<<<dim3(16), dim3(256), 0, stream>>>(
            t, Sh, Hnh, hbih, hbhh, hst[cur], masks, hst[nxt]);
    }

    write_hxs_k<<<dim3(3072), dim3(256), 0, stream>>>(fst[0], hst[0], out);
}

// Round 3
// 3851.475 us; speedup vs baseline: 5.8355x; 2.3483x over previous
//
#include <hip/hip_runtime.h>
#include <math.h>

typedef __attribute__((ext_vector_type(8))) __bf16 bf16x8;
typedef __attribute__((ext_vector_type(4))) float f32x4;

constexpr int H = 1024, T = 64, NB = 256, TWOH = 2048, THREEH = 3072;
constexpr long long OFF_Q  = 33554432LL;
constexpr long long OFF_HX = 67108864LL;

// Wbf row offsets (rows of 1024 bf16, byte stride 2048)
constexpr int R_PWH = 0, R_PWQ = 2048, R_QWF = 4096, R_QWC = 6144,
              R_FWIH = 8192, R_FWHH = 11264, R_HWIH = 14336, R_HWHH = 17408;

#define LD4(p) (*reinterpret_cast<const float4*>(p))

__device__ __forceinline__ float sigf(float x) { return 1.0f / (1.0f + expf(-x)); }

__device__ __forceinline__ void gload16(const void* g, void* l) {
    __builtin_amdgcn_global_load_lds(
        (const __attribute__((address_space(1))) uint32_t*)g,
        (__attribute__((address_space(3))) uint32_t*)l, 16, 0, 0);
}

// swizzled bf16 scalar store: logical [n][k] -> group (k>>3) ^ (n&7)
__device__ __forceinline__ void st_bf_swz(__bf16* base, int n, int k, float v) {
    base[(size_t)n * 1024 + (((k >> 3) ^ (n & 7)) << 3) + (k & 7)] = (__bf16)v;
}

// LDS byte offset within one 8KB 64x64 tile for logical row, k-group gl(0..7)
#define FRAGOFF(rloc, gl) (((rloc) << 7) + ((((gl)) ^ ((rloc) & 7)) << 4))

// ---------------------------------------------------------------- staging
__device__ __forceinline__ void stageAB(int tid, char* ALb, char* BLb,
                                        const char* Ag, const char* Bg, int kb) {
    const int w = tid >> 6, lane = tid & 63;
    const int r8 = lane >> 3;
    const size_t co = (size_t)((lane & 7) * 16) + (size_t)kb * 128;
    #pragma unroll
    for (int i = 0; i < 2; ++i) {
        const int row = w * 16 + i * 8 + r8;
        gload16(Ag + (size_t)row * 2048 + co, ALb + w * 2048 + i * 1024);
        gload16(Bg + (size_t)row * 2048 + co, BLb + w * 2048 + i * 1024);
    }
}

// ---------------------------------------------------------------- 64x64 GEMM core
// A,B bf16 row-swizzled; double-buffered LDS; one barrier/iter; 2-seg K.
__device__ __forceinline__ void mm64(
    int tid, char* sA, char* sB,
    const char* A0, const char* B0, int n0,
    const char* A1, const char* B1, int n1,
    f32x4 (&acc0)[2][2], f32x4 (&acc1)[2][2])
{
    const int lane = tid & 63, w = tid >> 6;
    const int l15 = lane & 15, lg = lane >> 4;
    const int wr = w >> 1, wc = w & 1;
    const int nit = n0 + n1;
    int aoff[2][2], boff[2][2];
    #pragma unroll
    for (int f = 0; f < 2; ++f)
        #pragma unroll
        for (int kk = 0; kk < 2; ++kk) {
            const int ra = wr * 32 + f * 16 + l15;
            const int rb = wc * 32 + f * 16 + l15;
            aoff[f][kk] = FRAGOFF(ra, kk * 4 + lg);
            boff[f][kk] = FRAGOFF(rb, kk * 4 + lg);
        }
    stageAB(tid, sA, sB, A0, B0, 0);
    for (int kb = 0; kb < nit; ++kb) {
        __syncthreads();
        const int kn = kb + 1;
        if (kn < nit) {
            const char* An = (kn < n0) ? A0 : A1;
            const char* Bn = (kn < n0) ? B0 : B1;
            stageAB(tid, sA + (kn & 1) * 8192, sB + (kn & 1) * 8192, An, Bn,
                    (kn < n0) ? kn : kn - n0);
        }
        char* Ab = sA + (kb & 1) * 8192;
        char* Bb = sB + (kb & 1) * 8192;
        bf16x8 af[2][2], bv[2][2];
        #pragma unroll
        for (int f = 0; f < 2; ++f)
            #pragma unroll
            for (int kk = 0; kk < 2; ++kk) {
                af[f][kk] = *reinterpret_cast<const bf16x8*>(Ab + aoff[f][kk]);
                bv[f][kk] = *reinterpret_cast<const bf16x8*>(Bb + boff[f][kk]);
            }
        if (kb < n0) {
            #pragma unroll
            for (int kk = 0; kk < 2; ++kk)
                #pragma unroll
                for (int fr = 0; fr < 2; ++fr)
                    #pragma unroll
                    for (int fc = 0; fc < 2; ++fc)
                        acc0[fr][fc] = __builtin_amdgcn_mfma_f32_16x16x32_bf16(
                            af[fr][kk], bv[fc][kk], acc0[fr][fc], 0, 0, 0);
        } else {
            #pragma unroll
            for (int kk = 0; kk < 2; ++kk)
                #pragma unroll
                for (int fr = 0; fr < 2; ++fr)
                    #pragma unroll
                    for (int fc = 0; fc < 2; ++fc)
                        acc1[fr][fc] = __builtin_amdgcn_mfma_f32_16x16x32_bf16(
                            af[fr][kk], bv[fc][kk], acc1[fr][fc], 0, 0, 0);
        }
    }
}

// ---------------------------------------------------------------- fused 3-gate GRU GEMM
// sB holds 2 bufs x 3 gate tiles (24KB each buf). n-gate split into gi/gh accs.
__device__ __forceinline__ void mm64g(
    int tid, char* sA, char* sB,
    const char* A0, int n0, const char* A1, int n1,
    const char* Bg0, const char* Bg1,
    f32x4 (&aR)[2][2], f32x4 (&aZ)[2][2], f32x4 (&aNi)[2][2], f32x4 (&aNh)[2][2])
{
    const int lane = tid & 63, w = tid >> 6;
    const int l15 = lane & 15, lg = lane >> 4;
    const int wr = w >> 1, wc = w & 1;
    const int nit = n0 + n1;
    int aoff[2][2], boff[2][2];
    #pragma unroll
    for (int f = 0; f < 2; ++f)
        #pragma unroll
        for (int kk = 0; kk < 2; ++kk) {
            const int ra = wr * 32 + f * 16 + l15;
            const int rb = wc * 32 + f * 16 + l15;
            aoff[f][kk] = FRAGOFF(ra, kk * 4 + lg);
            boff[f][kk] = FRAGOFF(rb, kk * 4 + lg);
        }
    auto stg = [&](int buf, int kb, const char* Ag, const char* Bg) {
        const int r8 = lane >> 3;
        const size_t co = (size_t)((lane & 7) * 16) + (size_t)kb * 128;
        #pragma unroll
        for (int i = 0; i < 2; ++i) {
            const int row = w * 16 + i * 8 + r8;
            gload16(Ag + (size_t)row * 2048 + co, sA + buf * 8192 + w * 2048 + i * 1024);
            #pragma unroll
            for (int g = 0; g < 3; ++g)
                gload16(Bg + (size_t)(g * 1024 + row) * 2048 + co,
                        sB + buf * 24576 + g * 8192 + w * 2048 + i * 1024);
        }
    };
    stg(0, 0, A0, Bg0);
    for (int kb = 0; kb < nit; ++kb) {
        __syncthreads();
        const int kn = kb + 1;
        if (kn < nit) {
            const char* An = (kn < n0) ? A0 : A1;
            const char* Bn = (kn < n0) ? Bg0 : Bg1;
            stg(kn & 1, (kn < n0) ? kn : kn - n0, An, Bn);
        }
        char* Ab = sA + (kb & 1) * 8192;
        char* Bb = sB + (kb & 1) * 24576;
        bf16x8 af[2][2];
        #pragma unroll
        for (int f = 0; f < 2; ++f)
            #pragma unroll
            for (int kk = 0; kk < 2; ++kk)
                af[f][kk] = *reinterpret_cast<const bf16x8*>(Ab + aoff[f][kk]);
        // gate r (g=0), z (g=1)
        #pragma unroll
        for (int g = 0; g < 2; ++g) {
            bf16x8 bv[2][2];
            #pragma unroll
            for (int f = 0; f < 2; ++f)
                #pragma unroll
                for (int kk = 0; kk < 2; ++kk)
                    bv[f][kk] = *reinterpret_cast<const bf16x8*>(Bb + g * 8192 + boff[f][kk]);
            if (g == 0) {
                #pragma unroll
                for (int kk = 0; kk < 2; ++kk)
                    #pragma unroll
                    for (int fr = 0; fr < 2; ++fr)
                        #pragma unroll
                        for (int fc = 0; fc < 2; ++fc)
                            aR[fr][fc] = __builtin_amdgcn_mfma_f32_16x16x32_bf16(
                                af[fr][kk], bv[fc][kk], aR[fr][fc], 0, 0, 0);
            } else {
                #pragma unroll
                for (int kk = 0; kk < 2; ++kk)
                    #pragma unroll
                    for (int fr = 0; fr < 2; ++fr)
                        #pragma unroll
                        for (int fc = 0; fc < 2; ++fc)
                            aZ[fr][fc] = __builtin_amdgcn_mfma_f32_16x16x32_bf16(
                                af[fr][kk], bv[fc][kk], aZ[fr][fc], 0, 0, 0);
            }
        }
        // gate n (g=2): split by segment
        {
            bf16x8 bv[2][2];
            #pragma unroll
            for (int f = 0; f < 2; ++f)
                #pragma unroll
                for (int kk = 0; kk < 2; ++kk)
                    bv[f][kk] = *reinterpret_cast<const bf16x8*>(Bb + 2 * 8192 + boff[f][kk]);
            if (kb < n0) {
                #pragma unroll
                for (int kk = 0; kk < 2; ++kk)
                    #pragma unroll
                    for (int fr = 0; fr < 2; ++fr)
                        #pragma unroll
                        for (int fc = 0; fc < 2; ++fc)
                            aNi[fr][fc] = __builtin_amdgcn_mfma_f32_16x16x32_bf16(
                                af[fr][kk], bv[fc][kk], aNi[fr][fc], 0, 0, 0);
            } else {
                #pragma unroll
                for (int kk = 0; kk < 2; ++kk)
                    #pragma unroll
                    for (int fr = 0; fr < 2; ++fr)
                        #pragma unroll
                        for (int fc = 0; fc < 2; ++fc)
                            aNh[fr][fc] = __builtin_amdgcn_mfma_f32_16x16x32_bf16(
                                af[fr][kk], bv[fc][kk], aNh[fr][fc], 0, 0, 0);
            }
        }
    }
}

// ---------------------------------------------------------------- prepass kernels
__global__ __launch_bounds__(256) void wcvt_k(
    const float* __restrict__ pW, const float* __restrict__ qW,
    const float* __restrict__ fWih, const float* __restrict__ fWhh,
    const float* __restrict__ hWih, const float* __restrict__ hWhh,
    __bf16* __restrict__ Wbf)
{
    const long i = (long)blockIdx.x * 256 + threadIdx.x;
    const int row = (int)(i >> 7);
    const int G   = (int)i & 127;
    const float* src; int stride; int koff = 0; int r;
    if (row < 2048)       { src = pW;   stride = 2056; koff = 0;    r = row; }
    else if (row < 4096)  { src = pW;   stride = 2056; koff = 1024; r = row - 2048; }
    else if (row < 6144)  { src = qW;   stride = 2056; koff = 0;    r = row - 4096; }
    else if (row < 8192)  { src = qW;   stride = 2056; koff = 1024; r = row - 6144; }
    else if (row < 11264) { src = fWih; stride = 1024; r = row - 8192; }
    else if (row < 14336) { src = fWhh; stride = 1024; r = row - 11264; }
    else if (row < 17408) { src = hWih; stride = 1024; r = row - 14336; }
    else                  { src = hWhh; stride = 1024; r = row - 17408; }
    const float* p = src + (long)r * stride + koff + G * 8;
    float4 a = LD4(p), b = LD4(p + 4);
    bf16x8 v;
    v[0] = (__bf16)a.x; v[1] = (__bf16)a.y; v[2] = (__bf16)a.z; v[3] = (__bf16)a.w;
    v[4] = (__bf16)b.x; v[5] = (__bf16)b.y; v[6] = (__bf16)b.z; v[7] = (__bf16)b.w;
    *reinterpret_cast<bf16x8*>(Wbf + (size_t)row * 1024 + ((G ^ (row & 7)) << 3)) = v;
}

__global__ __launch_bounds__(256) void ccvt_k(const float* __restrict__ c,
                                              __bf16* __restrict__ cbf) {
    const long i = (long)blockIdx.x * 256 + threadIdx.x;
    const int row = (int)(i >> 7);
    const int G   = (int)i & 127;
    const float* p = c + (size_t)row * 1024 + G * 8;
    float4 a = LD4(p), b = LD4(p + 4);
    bf16x8 v;
    v[0] = (__bf16)a.x; v[1] = (__bf16)a.y; v[2] = (__bf16)a.z; v[3] = (__bf16)a.w;
    v[4] = (__bf16)b.x; v[5] = (__bf16)b.y; v[6] = (__bf16)b.z; v[7] = (__bf16)b.w;
    *reinterpret_cast<bf16x8*>(cbf + (size_t)row * 1024 + ((G ^ (row & 7)) << 3)) = v;
}

__global__ __launch_bounds__(256) void init2_k(
    const float* __restrict__ hxs, const float* __restrict__ masks,
    float* __restrict__ fst0, float* __restrict__ hst0,
    __bf16* __restrict__ fbm0, __bf16* __restrict__ hbm0, __bf16* __restrict__ qmub0)
{
    const int idx = blockIdx.x * 256 + threadIdx.x;   // 0..98303
    const int arr = idx >> 15;
    const int g   = idx & 32767;
    const int n   = g >> 7;
    const int G   = g & 127;
    const float m0 = masks[n];
    const float* p = hxs + (size_t)n * THREEH + arr * 1024 + G * 8;
    float4 a = LD4(p), b = LD4(p + 4);
    __bf16* dstB = arr == 0 ? fbm0 : (arr == 1 ? hbm0 : qmub0);
    bf16x8 v;
    v[0] = (__bf16)(a.x * m0); v[1] = (__bf16)(a.y * m0);
    v[2] = (__bf16)(a.z * m0); v[3] = (__bf16)(a.w * m0);
    v[4] = (__bf16)(b.x * m0); v[5] = (__bf16)(b.y * m0);
    v[6] = (__bf16)(b.z * m0); v[7] = (__bf16)(b.w * m0);
    *reinterpret_cast<bf16x8*>(dstB + (size_t)n * 1024 + ((G ^ (n & 7)) << 3)) = v;
    if (arr < 2) {
        float* dstF = arr == 0 ? fst0 : hst0;
        *reinterpret_cast<float4*>(dstF + (size_t)n * 1024 + G * 8) = a;
        *reinterpret_cast<float4*>(dstF + (size_t)n * 1024 + G * 8 + 4) = b;
    }
}

// Xq prepass: out_q = c @ qWc^T + a @ qWa^T   (no bias, no mask)
__global__ __launch_bounds__(256) void xq_k(
    const __bf16* __restrict__ cbf, const char* __restrict__ Wb,
    const float* __restrict__ act, const float* __restrict__ qW,
    float* __restrict__ out)
{
    __shared__ char smem[32768];
    const int tid = threadIdx.x;
    const int lane = tid & 63, w = tid >> 6;
    const int l15 = lane & 15, lg = lane >> 4;
    const int wr = w >> 1, wc = w & 1;
    const int row0 = (blockIdx.x >> 5) * 64;
    const int col0 = (blockIdx.x & 31) * 64;
    f32x4 acc[2][2] = {};
    mm64(tid, smem, smem + 16384,
         (const char*)cbf + (size_t)row0 * 2048, Wb + (size_t)(R_QWC + col0) * 2048, 16,
         nullptr, nullptr, 0, acc, acc);
    #pragma unroll
    for (int fc = 0; fc < 2; ++fc) {
        const int gc = col0 + wc * 32 + fc * 16 + l15;
        const float* wp = qW + (size_t)gc * 2056 + 2048;
        float4 x0 = LD4(wp), x1 = LD4(wp + 4);
        #pragma unroll
        for (int fr = 0; fr < 2; ++fr)
            #pragma unroll
            for (int j = 0; j < 4; ++j) {
                const int n = row0 + wr * 32 + fr * 16 + lg * 4 + j;
                const float* ar = act + (size_t)n * 8;
                float4 a0 = LD4(ar), a1 = LD4(ar + 4);
                float dot = a0.x * x0.x + a0.y * x0.y + a0.z * x0.z + a0.w * x0.w
                          + a1.x * x1.x + a1.y * x1.y + a1.z * x1.z + a1.w * x1.w;
                out[OFF_Q + (size_t)n * TWOH + gc] = acc[fr][fc][j] + dot;
            }
    }
}

// ---------------------------------------------------------------- per-step kernel 1
// blocks [0,128) p, [128,256) q, [256,320) fused f-GRU
__global__ __launch_bounds__(256) void pqf_k(
    int t,
    const __bf16* __restrict__ hbm, const __bf16* __restrict__ qmub,
    __bf16* __restrict__ qmubN,
    const __bf16* __restrict__ fbm, const __bf16* __restrict__ cbf,
    const float* __restrict__ fstF, float* __restrict__ fstN, __bf16* __restrict__ fbmN,
    const float* __restrict__ masks, const float* __restrict__ act,
    const float* __restrict__ pW, const float* __restrict__ pb,
    const float* __restrict__ qb,
    const char* __restrict__ Wb,
    const float* __restrict__ fbih, const float* __restrict__ fbhh,
    __bf16* __restrict__ pmub,
    float* __restrict__ out)
{
    __shared__ char smem[65536];
    const int tid = threadIdx.x;
    const int lane = tid & 63, w = tid >> 6;
    const int l15 = lane & 15, lg = lane >> 4;
    const int wr = w >> 1, wc = w & 1;
    const float* mrow = masks + (size_t)t * NB;
    const float* mn   = masks + (size_t)(t + 1 < T ? t + 1 : t) * NB;
    int b = blockIdx.x;

    if (b < 256) {
        const int isQ = b >= 128; if (isQ) b -= 128;
        const int row0 = (b >> 5) * 64, col0 = (b & 31) * 64;
        f32x4 acc[2][2] = {};
        if (!isQ) {
            mm64(tid, smem, smem + 16384,
                 (const char*)hbm + (size_t)row0 * 2048, Wb + (size_t)(R_PWH + col0) * 2048, 16,
                 (const char*)qmub + (size_t)row0 * 2048, Wb + (size_t)(R_PWQ + col0) * 2048, 16,
                 acc, acc);
            float* ob = out + (size_t)t * NB * TWOH;
            #pragma unroll
            for (int fc = 0; fc < 2; ++fc) {
                const int gc = col0 + wc * 32 + fc * 16 + l15;
                const float* wp = pW + (size_t)gc * 2056 + 2048;
                float4 x0 = LD4(wp), x1 = LD4(wp + 4);
                const float bb = pb[gc];
                #pragma unroll
                for (int fr = 0; fr < 2; ++fr)
                    #pragma unroll
                    for (int j = 0; j < 4; ++j) {
                        const int n = row0 + wr * 32 + fr * 16 + lg * 4 + j;
                        const float* ar = act + ((size_t)t * NB + n) * 8;
                        float4 a0 = LD4(ar), a1 = LD4(ar + 4);
                        float dot = a0.x * x0.x + a0.y * x0.y + a0.z * x0.z + a0.w * x0.w
                                  + a1.x * x1.x + a1.y * x1.y + a1.z * x1.z + a1.w * x1.w;
                        float v = acc[fr][fc][j] + mrow[n] * dot + bb;
                        ob[(size_t)n * TWOH + gc] = v;
                        if (col0 < 1024) st_bf_swz(pmub, n, gc, v);   // p_mu (unmasked)
                    }
            }
        } else {
            mm64(tid, smem, smem + 16384,
                 (const char*)fbm + (size_t)row0 * 2048, Wb + (size_t)(R_QWF + col0) * 2048, 16,
                 nullptr, nullptr, 0, acc, acc);
            float* ob = out + OFF_Q + (size_t)t * NB * TWOH;
            #pragma unroll
            for (int fc = 0; fc < 2; ++fc) {
                const int gc = col0 + wc * 32 + fc * 16 + l15;
                const float bb = qb[gc];
                #pragma unroll
                for (int fr = 0; fr < 2; ++fr)
                    #pragma unroll
                    for (int j = 0; j < 4; ++j) {
                        const int n = row0 + wr * 32 + fr * 16 + lg * 4 + j;
                        const float xq = ob[(size_t)n * TWOH + gc];   // c@qWc + a@qWa
                        float v = acc[fr][fc][j] + mrow[n] * xq + bb;
                        ob[(size_t)n * TWOH + gc] = v;
                        if (col0 < 1024) st_bf_swz(qmubN, n, gc, v * mn[n]);
                    }
            }
        }
    } else {
        // fused f-GRU: gates + combine
        const int i = b - 256;
        const int row0 = (i >> 4) * 64, col0 = (i & 15) * 64;
        f32x4 aR[2][2] = {}, aZ[2][2] = {}, aNi[2][2] = {}, aNh[2][2] = {};
        mm64g(tid, smem, smem + 16384,
              (const char*)cbf + ((size_t)t * NB + row0) * 2048, 16,
              (const char*)fbm + (size_t)row0 * 2048, 16,
              Wb + (size_t)(R_FWIH + col0) * 2048, Wb + (size_t)(R_FWHH + col0) * 2048,
              aR, aZ, aNi, aNh);
        #pragma unroll
        for (int fc = 0; fc < 2; ++fc) {
            const int col = col0 + wc * 32 + fc * 16 + l15;
            const float br  = fbih[col] + fbhh[col];
            const float bz  = fbih[col + 1024] + fbhh[col + 1024];
            const float bni = fbih[col + 2048];
            const float bnh = fbhh[col + 2048];
            #pragma unroll
            for (int fr = 0; fr < 2; ++fr)
                #pragma unroll
                for (int j = 0; j < 4; ++j) {
                    const int n = row0 + wr * 32 + fr * 16 + lg * 4 + j;
                    const float rg = sigf(aR[fr][fc][j] + br);
                    const float zg = sigf(aZ[fr][fc][j] + bz);
                    const float ng = tanhf(aNi[fr][fc][j] + bni + rg * (aNh[fr][fc][j] + bnh));
                    const float hm = fstF[(size_t)n * 1024 + col] * mrow[n];
                    const float o = (1.f - zg) * ng + zg * hm;
                    fstN[(size_t)n * 1024 + col] = o;
                    st_bf_swz(fbmN, n, col, o * mn[n]);
                }
        }
    }
}

// ---------------------------------------------------------------- per-step kernel 2
// fused h-GRU: gates (pmu | h*m) + combine
__global__ __launch_bounds__(256) void hg_k(
    int t,
    const __bf16* __restrict__ pmub, const __bf16* __restrict__ hbm,
    const float* __restrict__ hstF, float* __restrict__ hstN, __bf16* __restrict__ hbmN,
    const char* __restrict__ Wb,
    const float* __restrict__ hbih, const float* __restrict__ hbhh,
    const float* __restrict__ masks)
{
    __shared__ char smem[65536];
    const int tid = threadIdx.x;
    const int lane = tid & 63, w = tid >> 6;
    const int l15 = lane & 15, lg = lane >> 4;
    const int wr = w >> 1, wc = w & 1;
    const float* mrow = masks + (size_t)t * NB;
    const float* mn   = masks + (size_t)(t + 1 < T ? t + 1 : t) * NB;
    const int i = blockIdx.x;
    const int row0 = (i >> 4) * 64, col0 = (i & 15) * 64;
    f32x4 aR[2][2] = {}, aZ[2][2] = {}, aNi[2][2] = {}, aNh[2][2] = {};
    mm64g(tid, smem, smem + 16384,
          (const char*)pmub + (size_t)row0 * 2048, 16,
          (const char*)hbm + (size_t)row0 * 2048, 16,
          Wb + (size_t)(R_HWIH + col0) * 2048, Wb + (size_t)(R_HWHH + col0) * 2048,
          aR, aZ, aNi, aNh);
    #pragma unroll
    for (int fc = 0; fc < 2; ++fc) {
        const int col = col0 + wc * 32 + fc * 16 + l15;
        const float br  = hbih[col] + hbhh[col];
        const float bz  = hbih[col + 1024] + hbhh[col + 1024];
        const float bni = hbih[col + 2048];
        const float bnh = hbhh[col + 2048];
        #pragma unroll
        for (int fr = 0; fr < 2; ++fr)
            #pragma unroll
            for (int j = 0; j < 4; ++j) {
                const int n = row0 + wr * 32 + fr * 16 + lg * 4 + j;
                const float rg = sigf(aR[fr][fc][j] + br);
                const float zg = sigf(aZ[fr][fc][j] + bz);
                const float ng = tanhf(aNi[fr][fc][j] + bni + rg * (aNh[fr][fc][j] + bnh));
                const float hm = hstF[(size_t)n * 1024 + col] * mrow[n];
                const float o = (1.f - zg) * ng + zg * hm;
                hstN[(size_t)n * 1024 + col] = o;
                st_bf_swz(hbmN, n, col, o * mn[n]);
            }
    }
}

// ---------------------------------------------------------------- final hxs
__global__ __launch_bounds__(256) void write_hxs_k(const float* __restrict__ fS,
                                                   const float* __restrict__ hS,
                                                   float* out) {
    const int i = blockIdx.x * 256 + threadIdx.x;
    const int n = i / THREEH;
    const int j = i - n * THREEH;
    float v;
    if (j < H)          v = fS[(size_t)n * H + j];
    else if (j < TWOH)  v = hS[(size_t)n * H + (j - H)];
    else                v = out[OFF_Q + ((size_t)(T - 1) * NB + n) * TWOH + (j - TWOH)];
    out[OFF_HX + i] = v;
}

// ---------------------------------------------------------------- launcher
extern "C" void kernel_launch(void* const* d_in, const int* in_sizes, int n_in,
                              void* d_out, int out_size, void* d_ws, size_t ws_size,
                              hipStream_t stream) {
    (void)in_sizes; (void)n_in; (void)out_size; (void)ws_size;

    const float* c     = (const float*)d_in[0];
    const float* hxs   = (const float*)d_in[1];
    const float* masks = (const float*)d_in[2];
    const float* act   = (const float*)d_in[3];
    const float* hWih  = (const float*)d_in[4];
    const float* hWhh  = (const float*)d_in[5];
    const float* hbih  = (const float*)d_in[6];
    const float* hbhh  = (const float*)d_in[7];
    const float* fWih  = (const float*)d_in[8];
    const float* fWhh  = (const float*)d_in[9];
    const float* fbih  = (const float*)d_in[10];
    const float* fbhh  = (const float*)d_in[11];
    const float* pW    = (const float*)d_in[12];
    const float* pb    = (const float*)d_in[13];
    const float* qW    = (const float*)d_in[14];
    const float* qb    = (const float*)d_in[15];

    float* out = (float*)d_out;
    char*  wsb = (char*)d_ws;

    __bf16* Wbf  = (__bf16*)(wsb);
    __bf16* cbf  = (__bf16*)(wsb + 41943040LL);
    float*  fst[2] = { (float*)(wsb + 75497472LL), (float*)(wsb + 76546048LL) };
    float*  hst[2] = { (float*)(wsb + 77594624LL), (float*)(wsb + 78643200LL) };
    __bf16* fbm[2] = { (__bf16*)(wsb + 79691776LL), (__bf16*)(wsb + 80216064LL) };
    __bf16* hbm[2] = { (__bf16*)(wsb + 80740352LL), (__bf16*)(wsb + 81264640LL) };
    __bf16* qmb[2] = { (__bf16*)(wsb + 81788928LL), (__bf16*)(wsb + 82313216LL) };
    __bf16* pmub   = (__bf16*)(wsb + 82837504LL);
    const char* Wb = (const char*)Wbf;

    wcvt_k <<<dim3(10240), dim3(256), 0, stream>>>(pW, qW, fWih, fWhh, hWih, hWhh, Wbf);
    ccvt_k <<<dim3(8192),  dim3(256), 0, stream>>>(c, cbf);
    init2_k<<<dim3(384),   dim3(256), 0, stream>>>(hxs, masks, fst[0], hst[0],
                                                   fbm[0], hbm[0], qmb[0]);
    xq_k   <<<dim3(8192),  dim3(256), 0, stream>>>(cbf, Wb, act, qW, out);

    for (int t = 0; t < T; ++t) {
        const int cur = t & 1, nxt = cur ^ 1;
        pqf_k<<<dim3(320), dim3(256), 0, stream>>>(
            t, hbm[cur], qmb[cur], qmb[nxt], fbm[cur], cbf,
            fst[cur], fst[nxt], fbm[nxt],
            masks, act, pW, pb, qb, Wb, fbih, fbhh, pmub, out);
        hg_k<<<dim3(64), dim3(256), 0, stream>>>(
            t, pmub, hbm[cur], hst[cur], hst[nxt], hbm[nxt],
            Wb, hbih, hbhh, masks);
    }

    write_hxs_k<<<dim3(3072), dim3(256), 0, stream>>>(fst[0], hst[0], out);
}

// Round 4
// 3121.781 us; speedup vs baseline: 7.1995x; 1.2337x over previous
//
#include <hip/hip_runtime.h>
#include <math.h>

typedef __attribute__((ext_vector_type(8))) __bf16 bf16x8;
typedef __attribute__((ext_vector_type(4))) float f32x4;

constexpr int H = 1024, T = 64, NB = 256, TWOH = 2048, THREEH = 3072;
constexpr long long OFF_Q  = 33554432LL;
constexpr long long OFF_HX = 67108864LL;

// Wbf row offsets (rows of 1024 bf16, byte stride 2048)
constexpr int R_PWH = 0, R_PWQ = 2048, R_QWF = 4096, R_QWC = 6144,
              R_FWIH = 8192, R_FWHH = 11264, R_HWIH = 14336, R_HWHH = 17408;

#define LD4(p) (*reinterpret_cast<const float4*>(p))

__device__ __forceinline__ float sigf(float x) { return 1.0f / (1.0f + expf(-x)); }

__device__ __forceinline__ void gload16(const void* g, void* l) {
    __builtin_amdgcn_global_load_lds(
        (const __attribute__((address_space(1))) uint32_t*)g,
        (__attribute__((address_space(3))) uint32_t*)l, 16, 0, 0);
}

// swizzled bf16 scalar store: logical [n][k] -> group (k>>3) ^ (n&7)
__device__ __forceinline__ void st_bf_swz(__bf16* base, int n, int k, float v) {
    base[(size_t)n * 1024 + (((k >> 3) ^ (n & 7)) << 3) + (k & 7)] = (__bf16)v;
}

// LDS byte offset within a (rows x 64) bf16 tile for logical row, k-group gl(0..7)
#define FRAGOFF(rloc, gl) (((rloc) << 7) + ((((gl)) ^ ((rloc) & 7)) << 4))

// stage RT rows x 64 k (RT*128 bytes) from pre-swizzled global (row stride 2048B)
template<int RT>
__device__ __forceinline__ void stage_tile(const char* g, char* l, int kb, int tid) {
    #pragma unroll
    for (int i = 0; i < RT / 32; ++i) {
        const int L = i * 4096 + tid * 16;
        gload16(g + (size_t)(L >> 7) * 2048 + (size_t)kb * 128 + (L & 127), l + L);
    }
}

// ---------------------------------------------------------------- 64x128 GEMM core
// 4 waves 2x2; wave quadrant 32x64; acc[2][4]. Double-buffered, 1 barrier/iter.
__device__ __forceinline__ void mm128(
    int tid, char* sA, char* sB,
    const char* A0, const char* B0, int n0,
    const char* A1, const char* B1, int n1,
    f32x4 (&acc)[2][4])
{
    const int lane = tid & 63, w = tid >> 6;
    const int l15 = lane & 15, lg = lane >> 4;
    const int wr = w >> 1, wc = w & 1;
    const int nit = n0 + n1;
    int aoff[2][2], boff[4][2];
    #pragma unroll
    for (int fr = 0; fr < 2; ++fr)
        #pragma unroll
        for (int kk = 0; kk < 2; ++kk)
            aoff[fr][kk] = FRAGOFF(wr * 32 + fr * 16 + l15, kk * 4 + lg);
    #pragma unroll
    for (int fc = 0; fc < 4; ++fc)
        #pragma unroll
        for (int kk = 0; kk < 2; ++kk)
            boff[fc][kk] = FRAGOFF(wc * 64 + fc * 16 + l15, kk * 4 + lg);

    stage_tile<64>(A0, sA, 0, tid);
    stage_tile<128>(B0, sB, 0, tid);
    for (int kb = 0; kb < nit; ++kb) {
        __syncthreads();
        const int kn = kb + 1;
        if (kn < nit) {
            const char* An = (kn < n0) ? A0 : A1;
            const char* Bn = (kn < n0) ? B0 : B1;
            const int kl = (kn < n0) ? kn : kn - n0;
            stage_tile<64>(An, sA + (kn & 1) * 8192, kl, tid);
            stage_tile<128>(Bn, sB + (kn & 1) * 16384, kl, tid);
        }
        char* Ab = sA + (kb & 1) * 8192;
        char* Bb = sB + (kb & 1) * 16384;
        bf16x8 af[2][2], bv[4][2];
        #pragma unroll
        for (int fr = 0; fr < 2; ++fr)
            #pragma unroll
            for (int kk = 0; kk < 2; ++kk)
                af[fr][kk] = *reinterpret_cast<const bf16x8*>(Ab + aoff[fr][kk]);
        #pragma unroll
        for (int fc = 0; fc < 4; ++fc)
            #pragma unroll
            for (int kk = 0; kk < 2; ++kk)
                bv[fc][kk] = *reinterpret_cast<const bf16x8*>(Bb + boff[fc][kk]);
        #pragma unroll
        for (int kk = 0; kk < 2; ++kk)
            #pragma unroll
            for (int fr = 0; fr < 2; ++fr)
                #pragma unroll
                for (int fc = 0; fc < 4; ++fc)
                    acc[fr][fc] = __builtin_amdgcn_mfma_f32_16x16x32_bf16(
                        af[fr][kk], bv[fc][kk], acc[fr][fc], 0, 0, 0);
    }
}

// ---------------------------------------------------------------- 32x64 3-gate GRU core
// 4 waves 2x2; wave quadrant 16x32; accs per gate [2]. n-gate split by segment.
__device__ __forceinline__ void mm32g(
    int tid, char* sA, char* sB,
    const char* A0, const char* B0g, int n0,
    const char* A1, const char* B1g, int n1,
    f32x4 (&aR)[2], f32x4 (&aZ)[2], f32x4 (&aNi)[2], f32x4 (&aNh)[2])
{
    const int lane = tid & 63, w = tid >> 6;
    const int l15 = lane & 15, lg = lane >> 4;
    const int wr = w >> 1, wc = w & 1;
    const int nit = n0 + n1;
    int aoff[2], boff[2][2];
    #pragma unroll
    for (int kk = 0; kk < 2; ++kk)
        aoff[kk] = FRAGOFF(wr * 16 + l15, kk * 4 + lg);
    #pragma unroll
    for (int fc = 0; fc < 2; ++fc)
        #pragma unroll
        for (int kk = 0; kk < 2; ++kk)
            boff[fc][kk] = FRAGOFF(wc * 32 + fc * 16 + l15, kk * 4 + lg);

    auto stg = [&](int buf, int kb, const char* Ag, const char* Bg) {
        stage_tile<32>(Ag, sA + buf * 4096, kb, tid);
        #pragma unroll
        for (int g = 0; g < 3; ++g)
            stage_tile<64>(Bg + (size_t)g * 2097152, sB + buf * 24576 + g * 8192, kb, tid);
    };
    stg(0, 0, A0, B0g);
    for (int kb = 0; kb < nit; ++kb) {
        __syncthreads();
        const int kn = kb + 1;
        if (kn < nit) {
            const char* An = (kn < n0) ? A0 : A1;
            const char* Bn = (kn < n0) ? B0g : B1g;
            stg(kn & 1, (kn < n0) ? kn : kn - n0, An, Bn);
        }
        char* Ab = sA + (kb & 1) * 4096;
        char* Bb = sB + (kb & 1) * 24576;
        bf16x8 af[2];
        #pragma unroll
        for (int kk = 0; kk < 2; ++kk)
            af[kk] = *reinterpret_cast<const bf16x8*>(Ab + aoff[kk]);
        // gates r, z
        #pragma unroll
        for (int g = 0; g < 2; ++g) {
            bf16x8 bv[2][2];
            #pragma unroll
            for (int fc = 0; fc < 2; ++fc)
                #pragma unroll
                for (int kk = 0; kk < 2; ++kk)
                    bv[fc][kk] = *reinterpret_cast<const bf16x8*>(Bb + g * 8192 + boff[fc][kk]);
            if (g == 0) {
                #pragma unroll
                for (int kk = 0; kk < 2; ++kk)
                    #pragma unroll
                    for (int fc = 0; fc < 2; ++fc)
                        aR[fc] = __builtin_amdgcn_mfma_f32_16x16x32_bf16(
                            af[kk], bv[fc][kk], aR[fc], 0, 0, 0);
            } else {
                #pragma unroll
                for (int kk = 0; kk < 2; ++kk)
                    #pragma unroll
                    for (int fc = 0; fc < 2; ++fc)
                        aZ[fc] = __builtin_amdgcn_mfma_f32_16x16x32_bf16(
                            af[kk], bv[fc][kk], aZ[fc], 0, 0, 0);
            }
        }
        // gate n
        {
            bf16x8 bv[2][2];
            #pragma unroll
            for (int fc = 0; fc < 2; ++fc)
                #pragma unroll
                for (int kk = 0; kk < 2; ++kk)
                    bv[fc][kk] = *reinterpret_cast<const bf16x8*>(Bb + 2 * 8192 + boff[fc][kk]);
            if (kb < n0) {
                #pragma unroll
                for (int kk = 0; kk < 2; ++kk)
                    #pragma unroll
                    for (int fc = 0; fc < 2; ++fc)
                        aNi[fc] = __builtin_amdgcn_mfma_f32_16x16x32_bf16(
                            af[kk], bv[fc][kk], aNi[fc], 0, 0, 0);
            } else {
                #pragma unroll
                for (int kk = 0; kk < 2; ++kk)
                    #pragma unroll
                    for (int fc = 0; fc < 2; ++fc)
                        aNh[fc] = __builtin_amdgcn_mfma_f32_16x16x32_bf16(
                            af[kk], bv[fc][kk], aNh[fc], 0, 0, 0);
            }
        }
    }
}

// ---------------------------------------------------------------- prepass kernels
__global__ __launch_bounds__(256) void wcvt_k(
    const float* __restrict__ pW, const float* __restrict__ qW,
    const float* __restrict__ fWih, const float* __restrict__ fWhh,
    const float* __restrict__ hWih, const float* __restrict__ hWhh,
    __bf16* __restrict__ Wbf)
{
    const long i = (long)blockIdx.x * 256 + threadIdx.x;
    const int row = (int)(i >> 7);
    const int G   = (int)i & 127;
    const float* src; int stride; int koff = 0; int r;
    if (row < 2048)       { src = pW;   stride = 2056; koff = 0;    r = row; }
    else if (row < 4096)  { src = pW;   stride = 2056; koff = 1024; r = row - 2048; }
    else if (row < 6144)  { src = qW;   stride = 2056; koff = 0;    r = row - 4096; }
    else if (row < 8192)  { src = qW;   stride = 2056; koff = 1024; r = row - 6144; }
    else if (row < 11264) { src = fWih; stride = 1024; r = row - 8192; }
    else if (row < 14336) { src = fWhh; stride = 1024; r = row - 11264; }
    else if (row < 17408) { src = hWih; stride = 1024; r = row - 14336; }
    else                  { src = hWhh; stride = 1024; r = row - 17408; }
    const float* p = src + (long)r * stride + koff + G * 8;
    float4 a = LD4(p), b = LD4(p + 4);
    bf16x8 v;
    v[0] = (__bf16)a.x; v[1] = (__bf16)a.y; v[2] = (__bf16)a.z; v[3] = (__bf16)a.w;
    v[4] = (__bf16)b.x; v[5] = (__bf16)b.y; v[6] = (__bf16)b.z; v[7] = (__bf16)b.w;
    *reinterpret_cast<bf16x8*>(Wbf + (size_t)row * 1024 + ((G ^ (row & 7)) << 3)) = v;
}

__global__ __launch_bounds__(256) void ccvt_k(const float* __restrict__ c,
                                              __bf16* __restrict__ cbf) {
    const long i = (long)blockIdx.x * 256 + threadIdx.x;
    const int row = (int)(i >> 7);
    const int G   = (int)i & 127;
    const float* p = c + (size_t)row * 1024 + G * 8;
    float4 a = LD4(p), b = LD4(p + 4);
    bf16x8 v;
    v[0] = (__bf16)a.x; v[1] = (__bf16)a.y; v[2] = (__bf16)a.z; v[3] = (__bf16)a.w;
    v[4] = (__bf16)b.x; v[5] = (__bf16)b.y; v[6] = (__bf16)b.z; v[7] = (__bf16)b.w;
    *reinterpret_cast<bf16x8*>(cbf + (size_t)row * 1024 + ((G ^ (row & 7)) << 3)) = v;
}

__global__ __launch_bounds__(256) void init2_k(
    const float* __restrict__ hxs, const float* __restrict__ masks,
    float* __restrict__ fst0, float* __restrict__ hst0,
    __bf16* __restrict__ fbm0, __bf16* __restrict__ hbm0, __bf16* __restrict__ qmub0)
{
    const int idx = blockIdx.x * 256 + threadIdx.x;
    const int arr = idx >> 15;
    const int g   = idx & 32767;
    const int n   = g >> 7;
    const int G   = g & 127;
    const float m0 = masks[n];
    const float* p = hxs + (size_t)n * THREEH + arr * 1024 + G * 8;
    float4 a = LD4(p), b = LD4(p + 4);
    __bf16* dstB = arr == 0 ? fbm0 : (arr == 1 ? hbm0 : qmub0);
    bf16x8 v;
    v[0] = (__bf16)(a.x * m0); v[1] = (__bf16)(a.y * m0);
    v[2] = (__bf16)(a.z * m0); v[3] = (__bf16)(a.w * m0);
    v[4] = (__bf16)(b.x * m0); v[5] = (__bf16)(b.y * m0);
    v[6] = (__bf16)(b.z * m0); v[7] = (__bf16)(b.w * m0);
    *reinterpret_cast<bf16x8*>(dstB + (size_t)n * 1024 + ((G ^ (n & 7)) << 3)) = v;
    if (arr < 2) {
        float* dstF = arr == 0 ? fst0 : hst0;
        *reinterpret_cast<float4*>(dstF + (size_t)n * 1024 + G * 8) = a;
        *reinterpret_cast<float4*>(dstF + (size_t)n * 1024 + G * 8 + 4) = b;
    }
}

// Xq prepass: out_q = c @ qWc^T + a @ qWa^T   (no bias, no mask)
__global__ __launch_bounds__(256) void xq_k(
    const __bf16* __restrict__ cbf, const char* __restrict__ Wb,
    const float* __restrict__ act, const float* __restrict__ qW,
    float* __restrict__ out)
{
    __shared__ char smem[49152];
    const int tid = threadIdx.x;
    const int lane = tid & 63, w = tid >> 6;
    const int l15 = lane & 15, lg = lane >> 4;
    const int wr = w >> 1, wc = w & 1;
    const int row0 = (blockIdx.x >> 4) * 64;
    const int col0 = (blockIdx.x & 15) * 128;
    f32x4 acc[2][4] = {};
    mm128(tid, smem, smem + 16384,
          (const char*)cbf + (size_t)row0 * 2048, Wb + (size_t)(R_QWC + col0) * 2048, 16,
          nullptr, nullptr, 0, acc);
    #pragma unroll
    for (int fc = 0; fc < 4; ++fc) {
        const int gc = col0 + wc * 64 + fc * 16 + l15;
        const float* wp = qW + (size_t)gc * 2056 + 2048;
        float4 x0 = LD4(wp), x1 = LD4(wp + 4);
        #pragma unroll
        for (int fr = 0; fr < 2; ++fr)
            #pragma unroll
            for (int j = 0; j < 4; ++j) {
                const int n = row0 + wr * 32 + fr * 16 + lg * 4 + j;
                const float* ar = act + (size_t)n * 8;
                float4 a0 = LD4(ar), a1 = LD4(ar + 4);
                float dot = a0.x * x0.x + a0.y * x0.y + a0.z * x0.z + a0.w * x0.w
                          + a1.x * x1.x + a1.y * x1.y + a1.z * x1.z + a1.w * x1.w;
                out[OFF_Q + (size_t)n * TWOH + gc] = acc[fr][fc][j] + dot;
            }
    }
}

// ---------------------------------------------------------------- per-step K1
// blocks [0,64) P, [64,128) Q, [128,224) h@hWhh -> Shh
__global__ __launch_bounds__(256) void k1_k(
    int t,
    const __bf16* __restrict__ hbm, const __bf16* __restrict__ qmub,
    __bf16* __restrict__ qmubN,
    const __bf16* __restrict__ fbm,
    const float* __restrict__ masks, const float* __restrict__ act,
    const float* __restrict__ pW, const float* __restrict__ pb,
    const float* __restrict__ qb,
    const char* __restrict__ Wb,
    __bf16* __restrict__ pmub, float* __restrict__ Shh,
    float* __restrict__ out)
{
    __shared__ char smem[49152];
    char* sA = smem;
    char* sB = smem + 16384;
    const int tid = threadIdx.x;
    const int lane = tid & 63, w = tid >> 6;
    const int l15 = lane & 15, lg = lane >> 4;
    const int wr = w >> 1, wc = w & 1;
    const float* mrow = masks + (size_t)t * NB;
    const float* mn   = masks + (size_t)(t + 1 < T ? t + 1 : t) * NB;
    int b = blockIdx.x;

    if (b < 64) {           // ---- P
        const int row0 = (b >> 4) * 64, col0 = (b & 15) * 128;
        f32x4 acc[2][4] = {};
        mm128(tid, sA, sB,
              (const char*)hbm + (size_t)row0 * 2048, Wb + (size_t)(R_PWH + col0) * 2048, 16,
              (const char*)qmub + (size_t)row0 * 2048, Wb + (size_t)(R_PWQ + col0) * 2048, 16,
              acc);
        float* ob = out + (size_t)t * NB * TWOH;
        #pragma unroll
        for (int fc = 0; fc < 4; ++fc) {
            const int gc = col0 + wc * 64 + fc * 16 + l15;
            const float* wp = pW + (size_t)gc * 2056 + 2048;
            float4 x0 = LD4(wp), x1 = LD4(wp + 4);
            const float bb = pb[gc];
            #pragma unroll
            for (int fr = 0; fr < 2; ++fr)
                #pragma unroll
                for (int j = 0; j < 4; ++j) {
                    const int n = row0 + wr * 32 + fr * 16 + lg * 4 + j;
                    const float* ar = act + ((size_t)t * NB + n) * 8;
                    float4 a0 = LD4(ar), a1 = LD4(ar + 4);
                    float dot = a0.x * x0.x + a0.y * x0.y + a0.z * x0.z + a0.w * x0.w
                              + a1.x * x1.x + a1.y * x1.y + a1.z * x1.z + a1.w * x1.w;
                    float v = acc[fr][fc][j] + mrow[n] * dot + bb;
                    ob[(size_t)n * TWOH + gc] = v;
                    if (gc < 1024) st_bf_swz(pmub, n, gc, v);
                }
        }
    } else if (b < 128) {   // ---- Q
        b -= 64;
        const int row0 = (b >> 4) * 64, col0 = (b & 15) * 128;
        f32x4 acc[2][4] = {};
        mm128(tid, sA, sB,
              (const char*)fbm + (size_t)row0 * 2048, Wb + (size_t)(R_QWF + col0) * 2048, 16,
              nullptr, nullptr, 0, acc);
        float* ob = out + OFF_Q + (size_t)t * NB * TWOH;
        #pragma unroll
        for (int fc = 0; fc < 4; ++fc) {
            const int gc = col0 + wc * 64 + fc * 16 + l15;
            const float bb = qb[gc];
            #pragma unroll
            for (int fr = 0; fr < 2; ++fr)
                #pragma unroll
                for (int j = 0; j < 4; ++j) {
                    const int n = row0 + wr * 32 + fr * 16 + lg * 4 + j;
                    const float xq = ob[(size_t)n * TWOH + gc];
                    float v = acc[fr][fc][j] + mrow[n] * xq + bb;
                    ob[(size_t)n * TWOH + gc] = v;
                    if (gc < 1024) st_bf_swz(qmubN, n, gc, v * mn[n]);
                }
        }
    } else {                // ---- h@hWhh partial -> Shh
        const int i = b - 128;
        const int row0 = (i / 24) * 64, col0 = (i % 24) * 128;
        f32x4 acc[2][4] = {};
        mm128(tid, sA, sB,
              (const char*)hbm + (size_t)row0 * 2048, Wb + (size_t)(R_HWHH + col0) * 2048, 16,
              nullptr, nullptr, 0, acc);
        #pragma unroll
        for (int fc = 0; fc < 4; ++fc) {
            const int gc = col0 + wc * 64 + fc * 16 + l15;
            #pragma unroll
            for (int fr = 0; fr < 2; ++fr)
                #pragma unroll
                for (int j = 0; j < 4; ++j) {
                    const int n = row0 + wr * 32 + fr * 16 + lg * 4 + j;
                    Shh[(size_t)n * THREEH + gc] = acc[fr][fc][j];
                }
        }
    }
}

// ---------------------------------------------------------------- per-step K2
// blocks [0,128) h-combine (pmu@hWih + Shh), [128,256) full f-GRU
__global__ __launch_bounds__(256) void k2_k(
    int t,
    const __bf16* __restrict__ pmub, const __bf16* __restrict__ hbm,
    const __bf16* __restrict__ fbm, const __bf16* __restrict__ cbf,
    const float* __restrict__ Shh,
    const float* __restrict__ hstF, float* __restrict__ hstN, __bf16* __restrict__ hbmN,
    const float* __restrict__ fstF, float* __restrict__ fstN, __bf16* __restrict__ fbmN,
    const char* __restrict__ Wb,
    const float* __restrict__ hbih, const float* __restrict__ hbhh,
    const float* __restrict__ fbih, const float* __restrict__ fbhh,
    const float* __restrict__ masks)
{
    __shared__ char smem[57344];
    char* sA = smem;
    char* sB = smem + 8192;
    const int tid = threadIdx.x;
    const int lane = tid & 63, w = tid >> 6;
    const int l15 = lane & 15, lg = lane >> 4;
    const int wr = w >> 1, wc = w & 1;
    const float* mrow = masks + (size_t)t * NB;
    const float* mn   = masks + (size_t)(t + 1 < T ? t + 1 : t) * NB;
    const int b = blockIdx.x;
    const int i = b & 127;
    const int row0 = (i >> 4) * 32, col0 = (i & 15) * 64;

    f32x4 aR[2] = {}, aZ[2] = {}, aNi[2] = {}, aNh[2] = {};
    if (b < 128) {
        mm32g(tid, sA, sB,
              (const char*)pmub + (size_t)row0 * 2048, Wb + (size_t)(R_HWIH + col0) * 2048, 16,
              nullptr, nullptr, 0, aR, aZ, aNi, aNh);
        #pragma unroll
        for (int fc = 0; fc < 2; ++fc) {
            const int col = col0 + wc * 32 + fc * 16 + l15;
            const float bri = hbih[col],        brh = hbhh[col];
            const float bzi = hbih[col + 1024], bzh = hbhh[col + 1024];
            const float bni = hbih[col + 2048], bnh = hbhh[col + 2048];
            #pragma unroll
            for (int j = 0; j < 4; ++j) {
                const int n = row0 + wr * 16 + lg * 4 + j;
                const float ghr = Shh[(size_t)n * THREEH + col];
                const float ghz = Shh[(size_t)n * THREEH + col + 1024];
                const float ghn = Shh[(size_t)n * THREEH + col + 2048];
                const float rg = sigf(aR[fc][j] + bri + ghr + brh);
                const float zg = sigf(aZ[fc][j] + bzi + ghz + bzh);
                const float ng = tanhf(aNi[fc][j] + bni + rg * (ghn + bnh));
                const float hm = hstF[(size_t)n * 1024 + col] * mrow[n];
                const float o = (1.f - zg) * ng + zg * hm;
                hstN[(size_t)n * 1024 + col] = o;
                st_bf_swz(hbmN, n, col, o * mn[n]);
            }
        }
    } else {
        mm32g(tid, sA, sB,
              (const char*)cbf + ((size_t)t * NB + row0) * 2048, Wb + (size_t)(R_FWIH + col0) * 2048, 16,
              (const char*)fbm + (size_t)row0 * 2048, Wb + (size_t)(R_FWHH + col0) * 2048, 16,
              aR, aZ, aNi, aNh);
        #pragma unroll
        for (int fc = 0; fc < 2; ++fc) {
            const int col = col0 + wc * 32 + fc * 16 + l15;
            const float br  = fbih[col] + fbhh[col];
            const float bz  = fbih[col + 1024] + fbhh[col + 1024];
            const float bni = fbih[col + 2048], bnh = fbhh[col + 2048];
            #pragma unroll
            for (int j = 0; j < 4; ++j) {
                const int n = row0 + wr * 16 + lg * 4 + j;
                const float rg = sigf(aR[fc][j] + br);
                const float zg = sigf(aZ[fc][j] + bz);
                const float ng = tanhf(aNi[fc][j] + bni + rg * (aNh[fc][j] + bnh));
                const float fm = fstF[(size_t)n * 1024 + col] * mrow[n];
                const float o = (1.f - zg) * ng + zg * fm;
                fstN[(size_t)n * 1024 + col] = o;
                st_bf_swz(fbmN, n, col, o * mn[n]);
            }
        }
    }
}

// ---------------------------------------------------------------- final hxs
__global__ __launch_bounds__(256) void write_hxs_k(const float* __restrict__ fS,
                                                   const float* __restrict__ hS,
                                                   float* out) {
    const int i = blockIdx.x * 256 + threadIdx.x;
    const int n = i / THREEH;
    const int j = i - n * THREEH;
    float v;
    if (j < H)          v = fS[(size_t)n * H + j];
    else if (j < TWOH)  v = hS[(size_t)n * H + (j - H)];
    else                v = out[OFF_Q + ((size_t)(T - 1) * NB + n) * TWOH + (j - TWOH)];
    out[OFF_HX + i] = v;
}

// ---------------------------------------------------------------- launcher
extern "C" void kernel_launch(void* const* d_in, const int* in_sizes, int n_in,
                              void* d_out, int out_size, void* d_ws, size_t ws_size,
                              hipStream_t stream) {
    (void)in_sizes; (void)n_in; (void)out_size; (void)ws_size;

    const float* c     = (const float*)d_in[0];
    const float* hxs   = (const float*)d_in[1];
    const float* masks = (const float*)d_in[2];
    const float* act   = (const float*)d_in[3];
    const float* hWih  = (const float*)d_in[4];
    const float* hWhh  = (const float*)d_in[5];
    const float* hbih  = (const float*)d_in[6];
    const float* hbhh  = (const float*)d_in[7];
    const float* fWih  = (const float*)d_in[8];
    const float* fWhh  = (const float*)d_in[9];
    const float* fbih  = (const float*)d_in[10];
    const float* fbhh  = (const float*)d_in[11];
    const float* pW    = (const float*)d_in[12];
    const float* pb    = (const float*)d_in[13];
    const float* qW    = (const float*)d_in[14];
    const float* qb    = (const float*)d_in[15];

    float* out = (float*)d_out;
    char*  wsb = (char*)d_ws;

    __bf16* Wbf  = (__bf16*)(wsb);
    __bf16* cbf  = (__bf16*)(wsb + 41943040LL);
    float*  fst[2] = { (float*)(wsb + 75497472LL), (float*)(wsb + 76546048LL) };
    float*  hst[2] = { (float*)(wsb + 77594624LL), (float*)(wsb + 78643200LL) };
    __bf16* fbm[2] = { (__bf16*)(wsb + 79691776LL), (__bf16*)(wsb + 80216064LL) };
    __bf16* hbm[2] = { (__bf16*)(wsb + 80740352LL), (__bf16*)(wsb + 81264640LL) };
    __bf16* qmb[2] = { (__bf16*)(wsb + 81788928LL), (__bf16*)(wsb + 82313216LL) };
    __bf16* pmub   = (__bf16*)(wsb + 82837504LL);
    float*  Shh    = (float*)(wsb + 83361792LL);     // 256x3072 f32, ends ~86.5MB
    const char* Wb = (const char*)Wbf;

    wcvt_k <<<dim3(10240), dim3(256), 0, stream>>>(pW, qW, fWih, fWhh, hWih, hWhh, Wbf);
    ccvt_k <<<dim3(8192),  dim3(256), 0, stream>>>(c, cbf);
    init2_k<<<dim3(384),   dim3(256), 0, stream>>>(hxs, masks, fst[0], hst[0],
                                                   fbm[0], hbm[0], qmb[0]);
    xq_k   <<<dim3(4096),  dim3(256), 0, stream>>>(cbf, Wb, act, qW, out);

    for (int t = 0; t < T; ++t) {
        const int cur = t & 1, nxt = cur ^ 1;
        k1_k<<<dim3(224), dim3(256), 0, stream>>>(
            t, hbm[cur], qmb[cur], qmb[nxt], fbm[cur],
            masks, act, pW, pb, qb, Wb, pmub, Shh, out);
        k2_k<<<dim3(256), dim3(256), 0, stream>>>(
            t, pmub, hbm[cur], fbm[cur], cbf, Shh,
            hst[cur], hst[nxt], hbm[nxt],
            fst[cur], fst[nxt], fbm[nxt],
            Wb, hbih, hbhh, fbih, fbhh, masks);
    }

    write_hxs_k<<<dim3(3072), dim3(256), 0, stream>>>(fst[0], hst[0], out);
}

// Round 6
// 2270.795 us; speedup vs baseline: 9.8976x; 1.3748x over previous
//
#include <hip/hip_runtime.h>
#include <math.h>

typedef __attribute__((ext_vector_type(8))) __bf16 bf16x8;
typedef __attribute__((ext_vector_type(4))) float f32x4;

constexpr int H = 1024, T = 64, NB = 256, TWOH = 2048, THREEH = 3072;
constexpr long long OFF_Q  = 33554432LL;
constexpr long long OFF_HX = 67108864LL;
constexpr int LA = 6;      // filler lookahead (ring of 8 slices)

// Wbf row offsets (rows of 1024 bf16, byte stride 2048)
constexpr int R_PWH = 0, R_PWQ = 2048, R_QWF = 4096, R_QWC = 6144,
              R_FWIH = 8192, R_FWHH = 11264, R_HWIH = 14336, R_HWHH = 17408;

#define LD4(p) (*reinterpret_cast<const float4*>(p))

__device__ __forceinline__ float sigf(float x) { return 1.0f / (1.0f + expf(-x)); }

__device__ __forceinline__ void gload16(const void* g, void* l) {
    __builtin_amdgcn_global_load_lds(
        (const __attribute__((address_space(1))) uint32_t*)g,
        (__attribute__((address_space(3))) uint32_t*)l, 16, 0, 0);
}

__device__ __forceinline__ void st_bf_swz(__bf16* base, int n, int k, float v) {
    base[(size_t)n * 1024 + (((k >> 3) ^ (n & 7)) << 3) + (k & 7)] = (__bf16)v;
}

#define FRAGOFF(rloc, gl) (((rloc) << 7) + ((((gl)) ^ ((rloc) & 7)) << 4))

// stage RT rows x 64 k from pre-swizzled global (row stride 2048B)
template<int RT>
__device__ __forceinline__ void stage_tile(const char* g, char* l, int kb, int tid) {
    #pragma unroll
    for (int i = 0; i < RT / 32; ++i) {
        const int L = i * 4096 + tid * 16;
        gload16(g + (size_t)(L >> 7) * 2048 + (size_t)kb * 128 + (L & 127), l + L);
    }
}

// ---------------------------------------------------------------- 64x128 GEMM core
// counted-vmcnt pipeline: stage(k+1) -> vmcnt(6) -> barrier -> frags+MFMA -> barrier
__device__ __forceinline__ void mm128(
    int tid, char* sA, char* sB,
    const char* A0, const char* B0, int n0,
    const char* A1, const char* B1, int n1,
    f32x4 (&acc)[2][4])
{
    const int lane = tid & 63, w = tid >> 6;
    const int l15 = lane & 15, lg = lane >> 4;
    const int wr = w >> 1, wc = w & 1;
    const int nit = n0 + n1;
    int aoff[2][2], boff[4][2];
    #pragma unroll
    for (int fr = 0; fr < 2; ++fr)
        #pragma unroll
        for (int kk = 0; kk < 2; ++kk)
            aoff[fr][kk] = FRAGOFF(wr * 32 + fr * 16 + l15, kk * 4 + lg);
    #pragma unroll
    for (int fc = 0; fc < 4; ++fc)
        #pragma unroll
        for (int kk = 0; kk < 2; ++kk)
            boff[fc][kk] = FRAGOFF(wc * 64 + fc * 16 + l15, kk * 4 + lg);

    stage_tile<64>(A0, sA, 0, tid);
    stage_tile<128>(B0, sB, 0, tid);
    for (int kb = 0; kb < nit; ++kb) {
        const int kn = kb + 1;
        if (kn < nit) {
            const char* An = (kn < n0) ? A0 : A1;
            const char* Bn = (kn < n0) ? B0 : B1;
            const int kl = (kn < n0) ? kn : kn - n0;
            stage_tile<64>(An, sA + (kn & 1) * 8192, kl, tid);
            stage_tile<128>(Bn, sB + (kn & 1) * 16384, kl, tid);
            asm volatile("s_waitcnt vmcnt(6)" ::: "memory");
        } else {
            asm volatile("s_waitcnt vmcnt(0)" ::: "memory");
        }
        __builtin_amdgcn_s_barrier();
        __builtin_amdgcn_sched_barrier(0);
        char* Ab = sA + (kb & 1) * 8192;
        char* Bb = sB + (kb & 1) * 16384;
        bf16x8 af[2][2], bv[4][2];
        #pragma unroll
        for (int fr = 0; fr < 2; ++fr)
            #pragma unroll
            for (int kk = 0; kk < 2; ++kk)
                af[fr][kk] = *reinterpret_cast<const bf16x8*>(Ab + aoff[fr][kk]);
        #pragma unroll
        for (int fc = 0; fc < 4; ++fc)
            #pragma unroll
            for (int kk = 0; kk < 2; ++kk)
                bv[fc][kk] = *reinterpret_cast<const bf16x8*>(Bb + boff[fc][kk]);
        __builtin_amdgcn_s_setprio(1);
        #pragma unroll
        for (int kk = 0; kk < 2; ++kk)
            #pragma unroll
            for (int fr = 0; fr < 2; ++fr)
                #pragma unroll
                for (int fc = 0; fc < 4; ++fc)
                    acc[fr][fc] = __builtin_amdgcn_mfma_f32_16x16x32_bf16(
                        af[fr][kk], bv[fc][kk], acc[fr][fc], 0, 0, 0);
        __builtin_amdgcn_s_setprio(0);
        __builtin_amdgcn_s_barrier();
        __builtin_amdgcn_sched_barrier(0);
    }
}

// ---------------------------------------------------------------- 32x64 1-seg 3-gate core
// K = 1024 -> 16 iterations of 64 (round-5 bug was 8).
__device__ __forceinline__ void mm32g1(
    int tid, char* sA, char* sB,
    const char* A, const char* Bg,
    f32x4 (&aR)[2], f32x4 (&aZ)[2], f32x4 (&aN)[2])
{
    const int lane = tid & 63, w = tid >> 6;
    const int l15 = lane & 15, lg = lane >> 4;
    const int wr = w >> 1, wc = w & 1;
    int aoff[2], boff[2][2];
    #pragma unroll
    for (int kk = 0; kk < 2; ++kk)
        aoff[kk] = FRAGOFF(wr * 16 + l15, kk * 4 + lg);
    #pragma unroll
    for (int fc = 0; fc < 2; ++fc)
        #pragma unroll
        for (int kk = 0; kk < 2; ++kk)
            boff[fc][kk] = FRAGOFF(wc * 32 + fc * 16 + l15, kk * 4 + lg);

    auto stg = [&](int buf, int kb) {
        stage_tile<32>(A, sA + buf * 4096, kb, tid);
        #pragma unroll
        for (int g = 0; g < 3; ++g)
            stage_tile<64>(Bg + (size_t)g * 2097152, sB + buf * 24576 + g * 8192, kb, tid);
    };
    stg(0, 0);
    for (int kb = 0; kb < 16; ++kb) {
        if (kb + 1 < 16) {
            stg((kb + 1) & 1, kb + 1);
            asm volatile("s_waitcnt vmcnt(7)" ::: "memory");
        } else {
            asm volatile("s_waitcnt vmcnt(0)" ::: "memory");
        }
        __builtin_amdgcn_s_barrier();
        __builtin_amdgcn_sched_barrier(0);
        char* Ab = sA + (kb & 1) * 4096;
        char* Bb = sB + (kb & 1) * 24576;
        bf16x8 af[2];
        #pragma unroll
        for (int kk = 0; kk < 2; ++kk)
            af[kk] = *reinterpret_cast<const bf16x8*>(Ab + aoff[kk]);
        bf16x8 bvr[2][2], bvz[2][2], bvn[2][2];
        #pragma unroll
        for (int fc = 0; fc < 2; ++fc)
            #pragma unroll
            for (int kk = 0; kk < 2; ++kk) {
                bvr[fc][kk] = *reinterpret_cast<const bf16x8*>(Bb + boff[fc][kk]);
                bvz[fc][kk] = *reinterpret_cast<const bf16x8*>(Bb + 8192 + boff[fc][kk]);
                bvn[fc][kk] = *reinterpret_cast<const bf16x8*>(Bb + 16384 + boff[fc][kk]);
            }
        __builtin_amdgcn_s_setprio(1);
        #pragma unroll
        for (int kk = 0; kk < 2; ++kk)
            #pragma unroll
            for (int fc = 0; fc < 2; ++fc) {
                aR[fc] = __builtin_amdgcn_mfma_f32_16x16x32_bf16(af[kk], bvr[fc][kk], aR[fc], 0, 0, 0);
                aZ[fc] = __builtin_amdgcn_mfma_f32_16x16x32_bf16(af[kk], bvz[fc][kk], aZ[fc], 0, 0, 0);
                aN[fc] = __builtin_amdgcn_mfma_f32_16x16x32_bf16(af[kk], bvn[fc][kk], aN[fc], 0, 0, 0);
            }
        __builtin_amdgcn_s_setprio(0);
        __builtin_amdgcn_s_barrier();
        __builtin_amdgcn_sched_barrier(0);
    }
}

// ---------------------------------------------------------------- filler bodies
// xq slice: out_q[slice rows] = c@qWc^T + a@qWa^T (no bias/mask). 64 blocks/slice.
__device__ __forceinline__ void do_xq(int slice, int i, int tid, char* sA, char* sB,
    const char* cbfB, const char* Wb, const float* act, const float* qW, float* out)
{
    const int lane = tid & 63, w = tid >> 6;
    const int l15 = lane & 15, lg = lane >> 4;
    const int wr = w >> 1, wc = w & 1;
    const int row0 = (i >> 4) * 64, col0 = (i & 15) * 128;
    const size_t grow0 = (size_t)slice * NB + row0;
    f32x4 acc[2][4] = {};
    mm128(tid, sA, sB, cbfB + grow0 * 2048, Wb + (size_t)(R_QWC + col0) * 2048, 16,
          nullptr, nullptr, 0, acc);
    #pragma unroll
    for (int fc = 0; fc < 4; ++fc) {
        const int gc = col0 + wc * 64 + fc * 16 + l15;
        const float* wp = qW + (size_t)gc * 2056 + 2048;
        float4 x0 = LD4(wp), x1 = LD4(wp + 4);
        #pragma unroll
        for (int fr = 0; fr < 2; ++fr)
            #pragma unroll
            for (int j = 0; j < 4; ++j) {
                const size_t n = grow0 + wr * 32 + fr * 16 + lg * 4 + j;
                const float* ar = act + n * 8;
                float4 a0 = LD4(ar), a1 = LD4(ar + 4);
                float dot = a0.x * x0.x + a0.y * x0.y + a0.z * x0.z + a0.w * x0.w
                          + a1.x * x1.x + a1.y * x1.y + a1.z * x1.z + a1.w * x1.w;
                out[OFF_Q + n * TWOH + gc] = acc[fr][fc][j] + dot;
            }
    }
}

// Gf slice: Gfb[slot] = c_t@fWih^T (bf16 ring). 96 blocks/slice.
__device__ __forceinline__ void do_gf(int slice, int i, int tid, char* sA, char* sB,
    const char* cbfB, const char* Wb, __bf16* Gfb)
{
    const int lane = tid & 63, w = tid >> 6;
    const int l15 = lane & 15, lg = lane >> 4;
    const int wr = w >> 1, wc = w & 1;
    const int row0 = (i / 24) * 64, col0 = (i % 24) * 128;
    f32x4 acc[2][4] = {};
    mm128(tid, sA, sB, cbfB + ((size_t)slice * NB + row0) * 2048,
          Wb + (size_t)(R_FWIH + col0) * 2048, 16, nullptr, nullptr, 0, acc);
    __bf16* gdst = Gfb + (size_t)(slice & 7) * NB * THREEH;
    #pragma unroll
    for (int fc = 0; fc < 4; ++fc) {
        const int gc = col0 + wc * 64 + fc * 16 + l15;
        #pragma unroll
        for (int fr = 0; fr < 2; ++fr)
            #pragma unroll
            for (int j = 0; j < 4; ++j) {
                const int n = row0 + wr * 32 + fr * 16 + lg * 4 + j;
                gdst[(size_t)n * THREEH + gc] = (__bf16)acc[fr][fc][j];
            }
    }
}

// ---------------------------------------------------------------- prepass kernels
__global__ __launch_bounds__(256) void wcvt_k(
    const float* __restrict__ pW, const float* __restrict__ qW,
    const float* __restrict__ fWih, const float* __restrict__ fWhh,
    const float* __restrict__ hWih, const float* __restrict__ hWhh,
    __bf16* __restrict__ Wbf)
{
    const long i = (long)blockIdx.x * 256 + threadIdx.x;
    const int row = (int)(i >> 7);
    const int G   = (int)i & 127;
    const float* src; int stride; int koff = 0; int r;
    if (row < 2048)       { src = pW;   stride = 2056; koff = 0;    r = row; }
    else if (row < 4096)  { src = pW;   stride = 2056; koff = 1024; r = row - 2048; }
    else if (row < 6144)  { src = qW;   stride = 2056; koff = 0;    r = row - 4096; }
    else if (row < 8192)  { src = qW;   stride = 2056; koff = 1024; r = row - 6144; }
    else if (row < 11264) { src = fWih; stride = 1024; r = row - 8192; }
    else if (row < 14336) { src = fWhh; stride = 1024; r = row - 11264; }
    else if (row < 17408) { src = hWih; stride = 1024; r = row - 14336; }
    else                  { src = hWhh; stride = 1024; r = row - 17408; }
    const float* p = src + (long)r * stride + koff + G * 8;
    float4 a = LD4(p), b = LD4(p + 4);
    bf16x8 v;
    v[0] = (__bf16)a.x; v[1] = (__bf16)a.y; v[2] = (__bf16)a.z; v[3] = (__bf16)a.w;
    v[4] = (__bf16)b.x; v[5] = (__bf16)b.y; v[6] = (__bf16)b.z; v[7] = (__bf16)b.w;
    *reinterpret_cast<bf16x8*>(Wbf + (size_t)row * 1024 + ((G ^ (row & 7)) << 3)) = v;
}

__global__ __launch_bounds__(256) void ccvt_k(const float* __restrict__ c,
                                              __bf16* __restrict__ cbf) {
    const long i = (long)blockIdx.x * 256 + threadIdx.x;
    const int row = (int)(i >> 7);
    const int G   = (int)i & 127;
    const float* p = c + (size_t)row * 1024 + G * 8;
    float4 a = LD4(p), b = LD4(p + 4);
    bf16x8 v;
    v[0] = (__bf16)a.x; v[1] = (__bf16)a.y; v[2] = (__bf16)a.z; v[3] = (__bf16)a.w;
    v[4] = (__bf16)b.x; v[5] = (__bf16)b.y; v[6] = (__bf16)b.z; v[7] = (__bf16)b.w;
    *reinterpret_cast<bf16x8*>(cbf + (size_t)row * 1024 + ((G ^ (row & 7)) << 3)) = v;
}

__global__ __launch_bounds__(256) void init2_k(
    const float* __restrict__ hxs, const float* __restrict__ masks,
    float* __restrict__ fst0, float* __restrict__ hst0,
    __bf16* __restrict__ fbm0, __bf16* __restrict__ hbm0, __bf16* __restrict__ qmub0)
{
    const int idx = blockIdx.x * 256 + threadIdx.x;
    const int arr = idx >> 15;
    const int g   = idx & 32767;
    const int n   = g >> 7;
    const int G   = g & 127;
    const float m0 = masks[n];
    const float* p = hxs + (size_t)n * THREEH + arr * 1024 + G * 8;
    float4 a = LD4(p), b = LD4(p + 4);
    __bf16* dstB = arr == 0 ? fbm0 : (arr == 1 ? hbm0 : qmub0);
    bf16x8 v;
    v[0] = (__bf16)(a.x * m0); v[1] = (__bf16)(a.y * m0);
    v[2] = (__bf16)(a.z * m0); v[3] = (__bf16)(a.w * m0);
    v[4] = (__bf16)(b.x * m0); v[5] = (__bf16)(b.y * m0);
    v[6] = (__bf16)(b.z * m0); v[7] = (__bf16)(b.w * m0);
    *reinterpret_cast<bf16x8*>(dstB + (size_t)n * 1024 + ((G ^ (n & 7)) << 3)) = v;
    if (arr < 2) {
        float* dstF = arr == 0 ? fst0 : hst0;
        *reinterpret_cast<float4*>(dstF + (size_t)n * 1024 + G * 8) = a;
        *reinterpret_cast<float4*>(dstF + (size_t)n * 1024 + G * 8 + 4) = b;
    }
}

// slices 0..LA-1 of xq and Gf
__global__ __launch_bounds__(256) void pre_k(
    const char* __restrict__ cbfB, const char* __restrict__ Wb,
    const float* __restrict__ act, const float* __restrict__ qW,
    __bf16* __restrict__ Gfb, float* __restrict__ out)
{
    __shared__ char smem[49152];
    const int s = blockIdx.x / 160;
    const int i = blockIdx.x % 160;
    if (i < 64) do_xq(s, i, threadIdx.x, smem, smem + 16384, cbfB, Wb, act, qW, out);
    else        do_gf(s, i - 64, threadIdx.x, smem, smem + 16384, cbfB, Wb, Gfb);
}

// ---------------------------------------------------------------- per-step K1
// [0,64) P | [64,128) Q | [128,224) h@hWhh->Shh | [224,288) xq(t+LA) | [288,384) Gf(t+LA)
__global__ __launch_bounds__(256) void k1_k(
    int t, int hasFiller,
    const __bf16* __restrict__ hbm, const __bf16* __restrict__ qmub,
    __bf16* __restrict__ qmubN,
    const __bf16* __restrict__ fbm, const char* __restrict__ cbfB,
    const float* __restrict__ masks, const float* __restrict__ act,
    const float* __restrict__ pW, const float* __restrict__ pb,
    const float* __restrict__ qb, const float* __restrict__ qW,
    const char* __restrict__ Wb,
    __bf16* __restrict__ pmub, float* __restrict__ Shh, __bf16* __restrict__ Gfb,
    float* __restrict__ out)
{
    __shared__ char smem[49152];
    char* sA = smem;
    char* sB = smem + 16384;
    const int tid = threadIdx.x;
    const int lane = tid & 63, w = tid >> 6;
    const int l15 = lane & 15, lg = lane >> 4;
    const int wr = w >> 1, wc = w & 1;
    const float* mrow = masks + (size_t)t * NB;
    const float* mn   = masks + (size_t)(t + 1 < T ? t + 1 : t) * NB;
    int b = blockIdx.x;

    if (b < 64) {           // ---- P
        const int row0 = (b >> 4) * 64, col0 = (b & 15) * 128;
        f32x4 acc[2][4] = {};
        mm128(tid, sA, sB,
              (const char*)hbm + (size_t)row0 * 2048, Wb + (size_t)(R_PWH + col0) * 2048, 16,
              (const char*)qmub + (size_t)row0 * 2048, Wb + (size_t)(R_PWQ + col0) * 2048, 16,
              acc);
        float* ob = out + (size_t)t * NB * TWOH;
        #pragma unroll
        for (int fc = 0; fc < 4; ++fc) {
            const int gc = col0 + wc * 64 + fc * 16 + l15;
            const float* wp = pW + (size_t)gc * 2056 + 2048;
            float4 x0 = LD4(wp), x1 = LD4(wp + 4);
            const float bb = pb[gc];
            #pragma unroll
            for (int fr = 0; fr < 2; ++fr)
                #pragma unroll
                for (int j = 0; j < 4; ++j) {
                    const int n = row0 + wr * 32 + fr * 16 + lg * 4 + j;
                    const float* ar = act + ((size_t)t * NB + n) * 8;
                    float4 a0 = LD4(ar), a1 = LD4(ar + 4);
                    float dot = a0.x * x0.x + a0.y * x0.y + a0.z * x0.z + a0.w * x0.w
                              + a1.x * x1.x + a1.y * x1.y + a1.z * x1.z + a1.w * x1.w;
                    float v = acc[fr][fc][j] + mrow[n] * dot + bb;
                    ob[(size_t)n * TWOH + gc] = v;
                    if (gc < 1024) st_bf_swz(pmub, n, gc, v);
                }
        }
    } else if (b < 128) {   // ---- Q
        b -= 64;
        const int row0 = (b >> 4) * 64, col0 = (b & 15) * 128;
        f32x4 acc[2][4] = {};
        mm128(tid, sA, sB,
              (const char*)fbm + (size_t)row0 * 2048, Wb + (size_t)(R_QWF + col0) * 2048, 16,
              nullptr, nullptr, 0, acc);
        float* ob = out + OFF_Q + (size_t)t * NB * TWOH;
        #pragma unroll
        for (int fc = 0; fc < 4; ++fc) {
            const int gc = col0 + wc * 64 + fc * 16 + l15;
            const float bb = qb[gc];
            #pragma unroll
            for (int fr = 0; fr < 2; ++fr)
                #pragma unroll
                for (int j = 0; j < 4; ++j) {
                    const int n = row0 + wr * 32 + fr * 16 + lg * 4 + j;
                    const float xq = ob[(size_t)n * TWOH + gc];
                    float v = acc[fr][fc][j] + mrow[n] * xq + bb;
                    ob[(size_t)n * TWOH + gc] = v;
                    if (gc < 1024) st_bf_swz(qmubN, n, gc, v * mn[n]);
                }
        }
    } else if (b < 224) {   // ---- h@hWhh -> Shh
        const int i = b - 128;
        const int row0 = (i / 24) * 64, col0 = (i % 24) * 128;
        f32x4 acc[2][4] = {};
        mm128(tid, sA, sB,
              (const char*)hbm + (size_t)row0 * 2048, Wb + (size_t)(R_HWHH + col0) * 2048, 16,
              nullptr, nullptr, 0, acc);
        #pragma unroll
        for (int fc = 0; fc < 4; ++fc) {
            const int gc = col0 + wc * 64 + fc * 16 + l15;
            #pragma unroll
            for (int fr = 0; fr < 2; ++fr)
                #pragma unroll
                for (int j = 0; j < 4; ++j) {
                    const int n = row0 + wr * 32 + fr * 16 + lg * 4 + j;
                    Shh[(size_t)n * THREEH + gc] = acc[fr][fc][j];
                }
        }
    } else if (b < 288) {   // ---- xq filler (slice t+LA)
        if (hasFiller) do_xq(t + LA, b - 224, tid, sA, sB, cbfB, Wb, act, qW, out);
    } else {                // ---- Gf filler (slice t+LA)
        if (hasFiller) do_gf(t + LA, b - 288, tid, sA, sB, cbfB, Wb, Gfb);
    }
}

// ---------------------------------------------------------------- per-step K2
// [0,128) h-GRU (pmu@hWih + Shh) | [128,256) f-GRU (f@fWhh + Gf)
__global__ __launch_bounds__(256) void k2_k(
    int t,
    const __bf16* __restrict__ pmub, const __bf16* __restrict__ hbm,
    const __bf16* __restrict__ fbm,
    const float* __restrict__ Shh, const __bf16* __restrict__ Gfb,
    const float* __restrict__ hstF, float* __restrict__ hstN, __bf16* __restrict__ hbmN,
    const float* __restrict__ fstF, float* __restrict__ fstN, __bf16* __restrict__ fbmN,
    const char* __restrict__ Wb,
    const float* __restrict__ hbih, const float* __restrict__ hbhh,
    const float* __restrict__ fbih, const float* __restrict__ fbhh,
    const float* __restrict__ masks)
{
    __shared__ char smem[57344];
    char* sA = smem;
    char* sB = smem + 8192;
    const int tid = threadIdx.x;
    const int lane = tid & 63, w = tid >> 6;
    const int l15 = lane & 15, lg = lane >> 4;
    const int wr = w >> 1, wc = w & 1;
    const float* mrow = masks + (size_t)t * NB;
    const float* mn   = masks + (size_t)(t + 1 < T ? t + 1 : t) * NB;
    const int b = blockIdx.x;
    const int i = b & 127;
    const int row0 = (i >> 4) * 32, col0 = (i & 15) * 64;

    f32x4 aR[2] = {}, aZ[2] = {}, aN[2] = {};
    if (b < 128) {
        mm32g1(tid, sA, sB,
               (const char*)pmub + (size_t)row0 * 2048,
               Wb + (size_t)(R_HWIH + col0) * 2048, aR, aZ, aN);
        #pragma unroll
        for (int fc = 0; fc < 2; ++fc) {
            const int col = col0 + wc * 32 + fc * 16 + l15;
            const float bri = hbih[col],        brh = hbhh[col];
            const float bzi = hbih[col + 1024], bzh = hbhh[col + 1024];
            const float bni = hbih[col + 2048], bnh = hbhh[col + 2048];
            #pragma unroll
            for (int j = 0; j < 4; ++j) {
                const int n = row0 + wr * 16 + lg * 4 + j;
                const float ghr = Shh[(size_t)n * THREEH + col];
                const float ghz = Shh[(size_t)n * THREEH + col + 1024];
                const float ghn = Shh[(size_t)n * THREEH + col + 2048];
                const float rg = sigf(aR[fc][j] + bri + ghr + brh);
                const float zg = sigf(aZ[fc][j] + bzi + ghz + bzh);
                const float ng = tanhf(aN[fc][j] + bni + rg * (ghn + bnh));
                const float hm = hstF[(size_t)n * 1024 + col] * mrow[n];
                const float o = (1.f - zg) * ng + zg * hm;
                hstN[(size_t)n * 1024 + col] = o;
                st_bf_swz(hbmN, n, col, o * mn[n]);
            }
        }
    } else {
        mm32g1(tid, sA, sB,
               (const char*)fbm + (size_t)row0 * 2048,
               Wb + (size_t)(R_FWHH + col0) * 2048, aR, aZ, aN);
        const __bf16* gsl = Gfb + (size_t)(t & 7) * NB * THREEH;
        #pragma unroll
        for (int fc = 0; fc < 2; ++fc) {
            const int col = col0 + wc * 32 + fc * 16 + l15;
            const float br  = fbih[col] + fbhh[col];
            const float bz  = fbih[col + 1024] + fbhh[col + 1024];
            const float bni = fbih[col + 2048], bnh = fbhh[col + 2048];
            #pragma unroll
            for (int j = 0; j < 4; ++j) {
                const int n = row0 + wr * 16 + lg * 4 + j;
                const float gfr = (float)gsl[(size_t)n * THREEH + col];
                const float gfz = (float)gsl[(size_t)n * THREEH + col + 1024];
                const float gfn = (float)gsl[(size_t)n * THREEH + col + 2048];
                const float rg = sigf(gfr + aR[fc][j] + br);
                const float zg = sigf(gfz + aZ[fc][j] + bz);
                const float ng = tanhf(gfn + bni + rg * (aN[fc][j] + bnh));
                const float fm = fstF[(size_t)n * 1024 + col] * mrow[n];
                const float o = (1.f - zg) * ng + zg * fm;
                fstN[(size_t)n * 1024 + col] = o;
                st_bf_swz(fbmN, n, col, o * mn[n]);
            }
        }
    }
}

// ---------------------------------------------------------------- final hxs
__global__ __launch_bounds__(256) void write_hxs_k(const float* __restrict__ fS,
                                                   const float* __restrict__ hS,
                                                   float* out) {
    const int i = blockIdx.x * 256 + threadIdx.x;
    const int n = i / THREEH;
    const int j = i - n * THREEH;
    float v;
    if (j < H)          v = fS[(size_t)n * H + j];
    else if (j < TWOH)  v = hS[(size_t)n * H + (j - H)];
    else                v = out[OFF_Q + ((size_t)(T - 1) * NB + n) * TWOH + (j - TWOH)];
    out[OFF_HX + i] = v;
}

// ---------------------------------------------------------------- launcher
extern "C" void kernel_launch(void* const* d_in, const int* in_sizes, int n_in,
                              void* d_out, int out_size, void* d_ws, size_t ws_size,
                              hipStream_t stream) {
    (void)in_sizes; (void)n_in; (void)out_size; (void)ws_size;

    const float* c     = (const float*)d_in[0];
    const float* hxs   = (const float*)d_in[1];
    const float* masks = (const float*)d_in[2];
    const float* act   = (const float*)d_in[3];
    const float* hWih  = (const float*)d_in[4];
    const float* hWhh  = (const float*)d_in[5];
    const float* hbih  = (const float*)d_in[6];
    const float* hbhh  = (const float*)d_in[7];
    const float* fWih  = (const float*)d_in[8];
    const float* fWhh  = (const float*)d_in[9];
    const float* fbih  = (const float*)d_in[10];
    const float* fbhh  = (const float*)d_in[11];
    const float* pW    = (const float*)d_in[12];
    const float* pb    = (const float*)d_in[13];
    const float* qW    = (const float*)d_in[14];
    const float* qb    = (const float*)d_in[15];

    float* out = (float*)d_out;
    char*  wsb = (char*)d_ws;

    __bf16* Wbf  = (__bf16*)(wsb);                               // 41.94 MB
    __bf16* cbf  = (__bf16*)(wsb + 41943040LL);                  // 33.55 MB
    float*  fst[2] = { (float*)(wsb + 75497472LL), (float*)(wsb + 76546048LL) };
    float*  hst[2] = { (float*)(wsb + 77594624LL), (float*)(wsb + 78643200LL) };
    __bf16* fbm[2] = { (__bf16*)(wsb + 79691776LL), (__bf16*)(wsb + 80216064LL) };
    __bf16* hbm[2] = { (__bf16*)(wsb + 80740352LL), (__bf16*)(wsb + 81264640LL) };
    __bf16* qmb[2] = { (__bf16*)(wsb + 81788928LL), (__bf16*)(wsb + 82313216LL) };
    __bf16* pmub   = (__bf16*)(wsb + 82837504LL);                // 0.52 MB
    float*  Shh    = (float*)(wsb + 83361792LL);                 // 3.15 MB
    __bf16* Gfb    = (__bf16*)(wsb + 86507520LL);                // 8 x 1.57 MB -> ends ~99.1 MB
    const char* Wb = (const char*)Wbf;
    const char* cbfB = (const char*)cbf;

    wcvt_k <<<dim3(10240), dim3(256), 0, stream>>>(pW, qW, fWih, fWhh, hWih, hWhh, Wbf);
    ccvt_k <<<dim3(8192),  dim3(256), 0, stream>>>(c, cbf);
    init2_k<<<dim3(384),   dim3(256), 0, stream>>>(hxs, masks, fst[0], hst[0],
                                                   fbm[0], hbm[0], qmb[0]);
    pre_k  <<<dim3(LA * 160), dim3(256), 0, stream>>>(cbfB, Wb, act, qW, Gfb, out);

    for (int t = 0; t < T; ++t) {
        const int cur = t & 1, nxt = cur ^ 1;
        const int hasF = (t + LA < T) ? 1 : 0;
        k1_k<<<dim3(hasF ? 384 : 224), dim3(256), 0, stream>>>(
            t, hasF, hbm[cur], qmb[cur], qmb[nxt], fbm[cur], cbfB,
            masks, act, pW, pb, qb, qW, Wb, pmub, Shh, Gfb, out);
        k2_k<<<dim3(256), dim3(256), 0, stream>>>(
            t, pmub, hbm[cur], fbm[cur], Shh, Gfb,
            hst[cur], hst[nxt], hbm[nxt],
            fst[cur], fst[nxt], fbm[nxt],
            Wb, hbih, hbhh, fbih, fbhh, masks);
    }

    write_hxs_k<<<dim3(3072), dim3(256), 0, stream>>>(fst[0], hst[0], out);
}